// Round 5
// baseline (7156.772 us; speedup 1.0000x reference)
//
#include <hip/hip_runtime.h>

#define FDIM 256
#define GRAM_KS 128
#define NODES_PER_ITEM 64

// ---------------- XCD id (verified on MI355X: s_getreg hwreg id 20) ----------------
__device__ __forceinline__ int get_xcc_id() {
  int x;
  // hwreg(20,0,32) -> simm16 = 20 | (31<<11) = 63508
  asm volatile("s_getreg_b32 %0, 63508" : "=s"(x));
  return x & 7;
}

// ---------------- CSR build ----------------
__global__ void k_hist(const int* __restrict__ dst, int* __restrict__ deg, int E) {
  int e = blockIdx.x * 256 + threadIdx.x;
  if (e < E) atomicAdd(&deg[dst[e]], 1);
}

__global__ __launch_bounds__(256) void k_blksum(const int* __restrict__ deg,
    int* __restrict__ blksum, int n) {
  int b = blockIdx.x, tid = threadIdx.x;
  int base = b * 1024 + tid * 4;
  int s = 0;
#pragma unroll
  for (int k = 0; k < 4; ++k) if (base + k < n) s += deg[base + k];
  for (int off = 32; off; off >>= 1) s += __shfl_down(s, off);
  __shared__ int ws4[4];
  if ((tid & 63) == 0) ws4[tid >> 6] = s;
  __syncthreads();
  if (tid == 0) blksum[b] = ws4[0] + ws4[1] + ws4[2] + ws4[3];
}

__global__ void k_blkscan(const int* __restrict__ blksum, int* __restrict__ blkoff, int nblk) {
  int lane = threadIdx.x;
  int carry = 0;
  for (int base = 0; base < nblk; base += 64) {
    int v = (base + lane < nblk) ? blksum[base + lane] : 0;
    int x = v;
    for (int off = 1; off < 64; off <<= 1) { int y = __shfl_up(x, off); if (lane >= off) x += y; }
    if (base + lane < nblk) blkoff[base + lane] = carry + x - v;
    carry += __shfl(x, 63);
  }
}

__global__ __launch_bounds__(256) void k_scan_blk(const int* __restrict__ deg,
    const int* __restrict__ blkoff, int* __restrict__ rowptr, int* __restrict__ cursor, int n) {
  int b = blockIdx.x, tid = threadIdx.x;
  int base = b * 1024 + tid * 4;
  int v[4];
#pragma unroll
  for (int k = 0; k < 4; ++k) v[k] = (base + k < n) ? deg[base + k] : 0;
  int s = v[0] + v[1] + v[2] + v[3];
  int lane = tid & 63, w = tid >> 6;
  int x = s;
  for (int off = 1; off < 64; off <<= 1) { int y = __shfl_up(x, off); if (lane >= off) x += y; }
  __shared__ int wsum[4];
  if (lane == 63) wsum[w] = x;
  __syncthreads();
  int wadd = 0;
  for (int i = 0; i < w; ++i) wadd += wsum[i];
  int run = blkoff[b] + wadd + x - s;
#pragma unroll
  for (int k = 0; k < 4; ++k) {
    if (base + k < n) { rowptr[base + k] = run; cursor[base + k] = run; }
    run += v[k];
  }
  if (n >= base && n <= base + 4) rowptr[n] = run;
}

__global__ void k_scatter(const int* __restrict__ src, const int* __restrict__ dst,
    int* __restrict__ cursor, int* __restrict__ esrc, int E) {
  int e = blockIdx.x * 256 + threadIdx.x;
  if (e < E) {
    int p = atomicAdd(&cursor[dst[e]], 1);
    esrc[p] = src[e];
  }
}

// ---------------- layout transform: row-major F -> planar FP ----------------
__global__ __launch_bounds__(256) void k_to_planar(const float* __restrict__ F,
    float* __restrict__ FP, int N) {
  int n = blockIdx.x * 4 + (threadIdx.x >> 6);
  int ic = threadIdx.x & 63;
#pragma unroll
  for (int q = 0; q < 4; ++q) {
    int col = q * 64 + ic;
    FP[((size_t)(col >> 4) * N + n) * 16 + (col & 15)] = F[(size_t)n * 256 + col];
  }
}

// ---------------- XCD-pinned planar aggregation with per-XCD work queues ----------------
// XCD x owns planes x (drained first) then x+8: concurrent per-XCD gather set = 3.2 MB < 4 MB L2.
// Work stealing after own queue empties guarantees completion under any block->XCD mapping.
__global__ __launch_bounds__(256) void k_aggp(const float* __restrict__ src,
    const int* __restrict__ rowptr, const int* __restrict__ esrc,
    float* __restrict__ out, int N, int* __restrict__ qctr, int rowmajor) {
  const int items_per_plane = (N + NODES_PER_ITEM - 1) / NODES_PER_ITEM;
  const int items_per_xcd = 2 * items_per_plane;
  __shared__ int s_item;
  const int xcd = get_xcc_id();
  const int lane = threadIdx.x & 63;
  const int wv = threadIdx.x >> 6;
  const int cl = lane & 15, es = lane >> 4;
  const size_t stride = rowmajor ? 256 : 16;
  for (int pass = 0; pass < 9; ++pass) {
    int q = (pass == 0) ? xcd : (pass - 1);
    if (pass > 0 && q == xcd) continue;
    while (true) {
      if (threadIdx.x == 0) s_item = atomicAdd(&qctr[q], 1);
      __syncthreads();
      int item = s_item;
      __syncthreads();
      if (item >= items_per_xcd) break;
      int sub = item / items_per_plane;
      int ig = item - sub * items_per_plane;
      int plane = q + 8 * sub;
      const float* base = rowmajor ? (src + plane * 16 + cl)
                                   : (src + (size_t)plane * N * 16 + cl);
      int nend = min(N, (ig + 1) * NODES_PER_ITEM);
      for (int n = ig * NODES_PER_ITEM + wv; n < nend; n += 4) {
        int beg = rowptr[n], end = rowptr[n + 1];
        float acc = 0.f;
        for (int e = beg + es; e < end; e += 4) {
          int s0 = __builtin_nontemporal_load(&esrc[e]);
          acc += base[(size_t)s0 * stride];
        }
        acc += __shfl_down(acc, 32);
        acc += __shfl_down(acc, 16);
        if (lane < 16)
          __builtin_nontemporal_store(acc, &out[((size_t)plane * N + n) * 16 + lane]);
      }
    }
  }
}

// ---------------- scalar aggregation ----------------
__global__ void k_deg(const int* __restrict__ rowptr, float* __restrict__ out, int n) {
  int v = blockIdx.x * 256 + threadIdx.x;
  if (v < n) out[v] = (float)(rowptr[v + 1] - rowptr[v]);
}

__global__ __launch_bounds__(256) void k_aggv(const float* __restrict__ in,
    const int* __restrict__ rowptr, const int* __restrict__ esrc,
    float* __restrict__ out, int n) {
  int wid = ((blockIdx.x * 256) + threadIdx.x) >> 6;
  int lane = threadIdx.x & 63;
  if (wid >= n) return;
  int beg = rowptr[wid], end = rowptr[wid + 1];
  float s = 0.f;
  for (int e = beg + lane; e < end; e += 64) s += in[esrc[e]];
  for (int off = 32; off; off >>= 1) s += __shfl_down(s, off);
  if (lane == 0) out[wid] = s;
}

// ---------------- Gram on planar inputs ----------------
__global__ __launch_bounds__(256) void k_gram(const float* __restrict__ Xm,
    const float* __restrict__ Ym, float* __restrict__ partial, int N) {
  __shared__ float Xs[16][132];
  __shared__ float Ys[16][132];
  int tid = threadIdx.x;
  int i0 = blockIdx.x * 128, j0 = blockIdx.y * 128;
  int z = blockIdx.z;
  int chunk = (N + GRAM_KS - 1) / GRAM_KS;
  int rb = z * chunk, re = min(N, rb + chunk);
  int lk = tid >> 4;
  int tj = tid & 15;
  int lc = tj * 8;
  int ti = lk;
  float acc[8][8] = {};
  for (int rr = rb; rr < re; rr += 16) {
    int r = rr + lk;
    float4 a0 = {0,0,0,0}, a1 = {0,0,0,0}, b0 = {0,0,0,0}, b1 = {0,0,0,0};
    if (r < re) {
      int Cx = i0 + lc, Cy = j0 + lc;
      const float* xp = Xm + ((size_t)(Cx >> 4) * N + r) * 16 + (Cx & 15);
      const float* yp = Ym + ((size_t)(Cy >> 4) * N + r) * 16 + (Cy & 15);
      a0 = *(const float4*)xp; a1 = *(const float4*)(xp + 4);
      b0 = *(const float4*)yp; b1 = *(const float4*)(yp + 4);
    }
    *(float4*)&Xs[lk][lc] = a0; *(float4*)&Xs[lk][lc + 4] = a1;
    *(float4*)&Ys[lk][lc] = b0; *(float4*)&Ys[lk][lc + 4] = b1;
    __syncthreads();
#pragma unroll
    for (int k = 0; k < 16; ++k) {
      float av[8], bv[8];
      *(float4*)&av[0] = *(const float4*)&Xs[k][ti * 4];
      *(float4*)&av[4] = *(const float4*)&Xs[k][64 + ti * 4];
      *(float4*)&bv[0] = *(const float4*)&Ys[k][tj * 4];
      *(float4*)&bv[4] = *(const float4*)&Ys[k][64 + tj * 4];
#pragma unroll
      for (int i = 0; i < 8; ++i)
#pragma unroll
        for (int j = 0; j < 8; ++j) acc[i][j] += av[i] * bv[j];
    }
    __syncthreads();
  }
  float* pout = partial + (size_t)z * 65536;
#pragma unroll
  for (int i = 0; i < 8; ++i) {
    int row = i0 + ((i < 4) ? (ti * 4 + i) : (64 + ti * 4 + i - 4));
#pragma unroll
    for (int j = 0; j < 8; j += 4) {
      int col = j0 + ((j < 4) ? (tj * 4 + j) : (64 + tj * 4 + j - 4));
      *(float4*)(pout + (size_t)row * 256 + col) = *(float4*)&acc[i][j];
    }
  }
}

__global__ void k_gram_reduce(const float* __restrict__ partial, float* __restrict__ C) {
  int idx = blockIdx.x * 256 + threadIdx.x;
  float s = 0.f;
  for (int z = 0; z < GRAM_KS; ++z) s += partial[(size_t)z * 65536 + idx];
  C[idx] = s;
}

// ---------------- weighted column sums (planar G) ----------------
__global__ __launch_bounds__(256) void k_matvec3(const float* __restrict__ G,
    const float* __restrict__ wA, const float* __restrict__ wB,
    float* outA, float* outB, float* outS, int n) {
  int f = threadIdx.x;
  size_t pbase = ((size_t)(f >> 4) * n) * 16 + (f & 15);
  float sA = 0.f, sB = 0.f, sS = 0.f;
  for (int r = blockIdx.x; r < n; r += gridDim.x) {
    float v = G[pbase + (size_t)r * 16];
    if (wA) sA += v * wA[r];
    if (wB) sB += v * wB[r];
    sS += v;
  }
  if (outA) atomicAdd(&outA[f], sA);
  if (outB) atomicAdd(&outB[f], sB);
  atomicAdd(&outS[f], sS);
}

// ---------------- 8 scalar reductions over d/e vectors ----------------
__global__ __launch_bounds__(256) void k_dots(const float* __restrict__ d1,
    const float* __restrict__ e1, const float* __restrict__ d2,
    const float* __restrict__ e2, float* scal, int n) {
  int i = blockIdx.x * 256 + threadIdx.x;
  float a = 0, b = 0, c = 0, d = 0;
  if (i < n) { a = d1[i]; b = e1[i]; c = d2[i]; d = e2[i]; }
  float v[8] = { b * d, b * c, b, a * d, a * c, a, d, c };
#pragma unroll
  for (int j = 0; j < 8; ++j) {
    float x = v[j];
    for (int off = 32; off; off >>= 1) x += __shfl_down(x, off);
    v[j] = x;
  }
  if ((threadIdx.x & 63) == 0)
#pragma unroll
    for (int j = 0; j < 8; ++j) atomicAdd(&scal[j], v[j]);
}

// ---------------- t_j = w_j^T C w_j ; mv_j = w_j . m_raw ----------------
__global__ __launch_bounds__(256) void k_quad(const float* __restrict__ C,
    const float* __restrict__ W1, const float* __restrict__ m_raw,
    float* __restrict__ t, float* __restrict__ mv) {
  __shared__ float w[256];
  __shared__ float r1[256], r2[256];
  int j = blockIdx.x, tid = threadIdx.x;
  w[tid] = W1[j * 256 + tid];
  __syncthreads();
  float v = 0.f;
  for (int k = 0; k < 256; ++k) v += w[k] * C[k * 256 + tid];
  r1[tid] = v * w[tid];
  r2[tid] = w[tid] * m_raw[tid];
  __syncthreads();
  for (int off = 128; off; off >>= 1) {
    if (tid < off) { r1[tid] += r1[tid + off]; r2[tid] += r2[tid + off]; }
    __syncthreads();
  }
  if (tid == 0) { t[j] = r1[0]; mv[j] = r2[0]; }
}

// ---------------- BN coefficients + x = W3 W2 c, y = W3 b2 ----------------
__global__ __launch_bounds__(256) void k_bncoef(const float* __restrict__ t,
    const float* __restrict__ mv, const float* __restrict__ b1,
    const float* __restrict__ gamma, const float* __restrict__ beta,
    const float* __restrict__ W2, const float* __restrict__ W3,
    const float* __restrict__ b2, float* Dv, float* xv, float* yv, int n) {
  __shared__ float c[256], u[256];
  int j = threadIdx.x;
  float invn = 1.f / (float)n;
  float mean = mv[j] * invn + b1[j];
  float E2 = t[j] * invn + 2.f * b1[j] * mv[j] * invn + b1[j] * b1[j];
  float var = E2 - mean * mean;
  float D = gamma[j] * rsqrtf(var + 1e-5f);
  Dv[j] = D;
  c[j] = D * (b1[j] - mean) + beta[j];
  __syncthreads();
  float uu = 0.f;
  for (int k = 0; k < 256; ++k) uu += W2[j * 256 + k] * c[k];
  u[j] = uu;
  __syncthreads();
  float xx = 0.f, yy = 0.f;
  for (int k = 0; k < 256; ++k) {
    xx += W3[j * 256 + k] * u[k];
    yy += W3[j * 256 + k] * b2[k];
  }
  xv[j] = xx;
  yv[j] = yy;
}

// ---------------- small 256x256 matmul ----------------
__global__ __launch_bounds__(256) void k_mm_small(float* __restrict__ Cm,
    const float* __restrict__ A, const float* __restrict__ B,
    const float* __restrict__ s, int transA, int transB, int accum) {
  __shared__ float a[256];
  int i = blockIdx.x, j = threadIdx.x;
  float av = transA ? A[j * 256 + i] : A[i * 256 + j];
  a[j] = s ? av * s[j] : av;
  __syncthreads();
  float acc = 0.f;
  if (transB) {
    for (int k = 0; k < 256; ++k) acc += a[k] * B[j * 256 + k];
  } else {
    for (int k = 0; k < 256; ++k) acc += a[k] * B[k * 256 + j];
  }
  if (accum) Cm[i * 256 + j] += acc;
  else Cm[i * 256 + j] = acc;
}

// ---------------- C (+)= u1 v1^T + u2 v2^T + u3 v3^T ----------------
__global__ void k_r1x3(float* __restrict__ C, const float* __restrict__ u1,
    const float* __restrict__ v1, const float* __restrict__ u2,
    const float* __restrict__ v2, const float* __restrict__ u3,
    const float* __restrict__ v3, int accum) {
  int i = blockIdx.x, j = threadIdx.x;
  float val = u1[i] * v1[j] + u2[i] * v2[j] + u3[i] * v3[j];
  if (accum) C[i * 256 + j] += val;
  else C[i * 256 + j] = val;
}

__global__ void k_mixvec(const float* __restrict__ scal, const float* __restrict__ x2,
    const float* __restrict__ yv, const float* __restrict__ b3,
    float* s1, float* s2, float* s3, float fN) {
  int j = threadIdx.x;
  s1[j] = scal[0] * x2[j] + scal[1] * yv[j] + scal[2] * b3[j];
  s2[j] = scal[3] * x2[j] + scal[4] * yv[j] + scal[5] * b3[j];
  s3[j] = scal[6] * x2[j] + scal[7] * yv[j] + fN * b3[j];
}

extern "C" void kernel_launch(void* const* d_in, const int* in_sizes, int n_in,
                              void* d_out, int out_size, void* d_ws, size_t ws_size,
                              hipStream_t stream) {
  const float* feature = (const float*)d_in[0];
  const int* src1 = (const int*)d_in[1];
  const int* dst1 = (const int*)d_in[2];
  const int* src2 = (const int*)d_in[3];
  const int* dst2 = (const int*)d_in[4];
  const float* W1 = (const float*)d_in[5];
  const float* b1 = (const float*)d_in[6];
  const float* W2 = (const float*)d_in[7];
  const float* b2 = (const float*)d_in[8];
  const float* W3 = (const float*)d_in[9];
  const float* b3 = (const float*)d_in[10];
  const float* gamma = (const float*)d_in[11];
  const float* beta = (const float*)d_in[12];
  const int N = in_sizes[0] / FDIM;
  const int E = in_sizes[1];
  float* out = (float*)d_out;

  // ---- workspace layout ----
  float* X = (float*)d_ws;
  size_t NF = (size_t)N * FDIM;
  float* Y = X + NF;
  float* G2A = Y + NF;
  int* rowptr = (int*)(G2A + NF);
  int* cursor = rowptr + (N + 1);
  int* esrc = cursor + N;
  float* vtmp = (float*)(esrc + E);
  float* d1 = vtmp + N; float* e1 = d1 + N; float* d2 = e1 + N; float* e2 = d2 + N;
  float* C = e2 + N;
  float* m_raw = C + 65536;
  float* tq = m_raw + 256; float* mv = tq + 256;
  float* Dv = mv + 256; float* x1 = Dv + 256; float* x2 = x1 + 256; float* yv = x2 + 256;
  float* Q = yv + 256; float* R1 = Q + 65536; float* R2 = R1 + 65536;
  float* Z = R2 + 65536; float* K1 = Z + 65536; float* Lm = K1 + 65536;
  float* p1 = Lm + 65536; float* p2 = p1 + 256; float* p3 = p2 + 256;
  float* q1 = p3 + 256; float* q2 = q1 + 256; float* q3 = q2 + 256;
  float* scal = q3 + 256;
  float* s1 = scal + 16; float* s2 = s1 + 256; float* s3 = s2 + 256;
  int* blksum = (int*)(s3 + 256);
  int* blkoff = blksum + 1024;
  int* qctr = blkoff + 1024;          // 12 dispatches x 8 XCD queues
  float* FP = (float*)(qctr + 128);
  float* partial = X;   // GRAM_KS*65536 floats <= NF; X dead at gram time

  size_t need = (size_t)((char*)(FP + NF) - (char*)d_ws);
  int havePlanar = (ws_size >= need) ? 1 : 0;

  const int eb = (E + 255) / 256;
  const int nb = (N + 255) / 256;
  const int aggb = (N + 3) / 4;
  const int nblk = (N + 1023) / 1024;

  hipMemsetAsync(qctr, 0, 128 * sizeof(int), stream);
  int agg_idx = 0;

  auto build = [&](const int* s_, const int* d_) {
    hipMemsetAsync(cursor, 0, (size_t)N * sizeof(int), stream);
    k_hist<<<eb, 256, 0, stream>>>(d_, cursor, E);
    k_blksum<<<nblk, 256, 0, stream>>>(cursor, blksum, N);
    k_blkscan<<<1, 64, 0, stream>>>(blksum, blkoff, nblk);
    k_scan_blk<<<nblk, 256, 0, stream>>>(cursor, blkoff, rowptr, cursor, N);
    k_scatter<<<eb, 256, 0, stream>>>(s_, d_, cursor, esrc, E);
  };
  auto agg = [&](const float* in, float* o, int rowmajor) {
    k_aggp<<<2048, 256, 0, stream>>>(in, rowptr, esrc, o, N, qctr + 8 * agg_idx, rowmajor);
    agg_idx++;
  };
  auto gram = [&](const float* A_, const float* B_, float* Cout) {
    k_gram<<<dim3(2, 2, GRAM_KS), 256, 0, stream>>>(A_, B_, partial, N);
    k_gram_reduce<<<256, 256, 0, stream>>>(partial, Cout);
  };

  if (havePlanar) k_to_planar<<<(N + 3) / 4, 256, 0, stream>>>(feature, FP, N);

  auto do_branch = [&](const int* s_, const int* d_, float* G2dst,
                       float* dvec, float* evec, float* xvec, float* Rdst) {
    build(s_, d_);
    if (havePlanar) agg(FP, X, 0); else agg(feature, X, 1);
    agg(X, Y, 0);                               // Y = G0 (planar)
    gram(Y, Y, C);                              // C = G0^T G0
    hipMemsetAsync(m_raw, 0, 256 * sizeof(float), stream);
    k_matvec3<<<512, 256, 0, stream>>>(Y, nullptr, nullptr, nullptr, nullptr, m_raw, N);
    k_quad<<<256, 256, 0, stream>>>(C, W1, m_raw, tq, mv);
    k_bncoef<<<1, 256, 0, stream>>>(tq, mv, b1, gamma, beta, W2, W3, b2, Dv, xvec, yv, N);
    k_mm_small<<<256, 256, 0, stream>>>(Q, W1, W2, Dv, 1, 1, 0);
    k_mm_small<<<256, 256, 0, stream>>>(Rdst, Q, W3, nullptr, 0, 1, 0);
    k_deg<<<nb, 256, 0, stream>>>(rowptr, vtmp, N);
    k_aggv<<<aggb, 256, 0, stream>>>(vtmp, rowptr, esrc, dvec, N);   // d = A^2 1
    k_aggv<<<aggb, 256, 0, stream>>>(dvec, rowptr, esrc, vtmp, N);
    k_aggv<<<aggb, 256, 0, stream>>>(vtmp, rowptr, esrc, evec, N);   // e = A^4 1
    agg(Y, X, 0); agg(X, Y, 0);                 // Y = G1
    agg(Y, X, 0); agg(X, G2dst, 0);             // G2
  };

  do_branch(src1, dst1, G2A, d1, e1, x1, R1);
  do_branch(src2, dst2, Y, d2, e2, x2, R2);

  // ---- final assembly ----
  hipMemsetAsync(p1, 0, (6 * 256 + 16) * sizeof(float), stream);
  gram(G2A, Y, Z);                                                // Z = G2_1^T G2_2
  k_matvec3<<<512, 256, 0, stream>>>(G2A, e2, d2, p1, p2, p3, N);
  k_matvec3<<<512, 256, 0, stream>>>(Y, e1, d1, q1, q2, q3, N);
  k_dots<<<nb, 256, 0, stream>>>(d1, e1, d2, e2, scal, N);

  k_mm_small<<<256, 256, 0, stream>>>(K1, Z, R2, nullptr, 0, 0, 0);
  k_r1x3<<<256, 256, 0, stream>>>(K1, p1, x2, p2, yv, p3, b3, 1);
  k_r1x3<<<256, 256, 0, stream>>>(Lm, x1, q1, yv, q2, b3, q3, 0);
  k_mm_small<<<256, 256, 0, stream>>>(out, R1, K1, nullptr, 1, 0, 0);
  k_mm_small<<<256, 256, 0, stream>>>(out, Lm, R2, nullptr, 0, 0, 1);
  k_mixvec<<<1, 256, 0, stream>>>(scal, x2, yv, b3, s1, s2, s3, (float)N);
  k_r1x3<<<256, 256, 0, stream>>>(out, x1, s1, yv, s2, b3, s3, 1);
}

// Round 6
// 5238.703 us; speedup vs baseline: 1.3661x; 1.3661x over previous
//
#include <hip/hip_runtime.h>

#define FDIM 256
#define GRAM_KS 128
#define NPI 64        // nodes per work item
#define MAXE 4096     // LDS-staged edge capacity per item

typedef __attribute__((ext_vector_type(4))) float fv4;

// ---------------- XCD id (verified on MI355X: s_getreg hwreg id 20) ----------------
__device__ __forceinline__ int get_xcc_id() {
  int x;
  asm volatile("s_getreg_b32 %0, 63508" : "=s"(x));  // hwreg(20,0,32)
  return x & 7;
}

// ---------------- CSR build ----------------
__global__ void k_hist(const int* __restrict__ dst, int* __restrict__ deg, int E) {
  int e = blockIdx.x * 256 + threadIdx.x;
  if (e < E) atomicAdd(&deg[dst[e]], 1);
}

__global__ __launch_bounds__(256) void k_blksum(const int* __restrict__ deg,
    int* __restrict__ blksum, int n) {
  int b = blockIdx.x, tid = threadIdx.x;
  int base = b * 1024 + tid * 4;
  int s = 0;
#pragma unroll
  for (int k = 0; k < 4; ++k) if (base + k < n) s += deg[base + k];
  for (int off = 32; off; off >>= 1) s += __shfl_down(s, off);
  __shared__ int ws4[4];
  if ((tid & 63) == 0) ws4[tid >> 6] = s;
  __syncthreads();
  if (tid == 0) blksum[b] = ws4[0] + ws4[1] + ws4[2] + ws4[3];
}

__global__ void k_blkscan(const int* __restrict__ blksum, int* __restrict__ blkoff, int nblk) {
  int lane = threadIdx.x;
  int carry = 0;
  for (int base = 0; base < nblk; base += 64) {
    int v = (base + lane < nblk) ? blksum[base + lane] : 0;
    int x = v;
    for (int off = 1; off < 64; off <<= 1) { int y = __shfl_up(x, off); if (lane >= off) x += y; }
    if (base + lane < nblk) blkoff[base + lane] = carry + x - v;
    carry += __shfl(x, 63);
  }
}

__global__ __launch_bounds__(256) void k_scan_blk(const int* __restrict__ deg,
    const int* __restrict__ blkoff, int* __restrict__ rowptr, int* __restrict__ cursor, int n) {
  int b = blockIdx.x, tid = threadIdx.x;
  int base = b * 1024 + tid * 4;
  int v[4];
#pragma unroll
  for (int k = 0; k < 4; ++k) v[k] = (base + k < n) ? deg[base + k] : 0;
  int s = v[0] + v[1] + v[2] + v[3];
  int lane = tid & 63, w = tid >> 6;
  int x = s;
  for (int off = 1; off < 64; off <<= 1) { int y = __shfl_up(x, off); if (lane >= off) x += y; }
  __shared__ int wsum[4];
  if (lane == 63) wsum[w] = x;
  __syncthreads();
  int wadd = 0;
  for (int i = 0; i < w; ++i) wadd += wsum[i];
  int run = blkoff[b] + wadd + x - s;
#pragma unroll
  for (int k = 0; k < 4; ++k) {
    if (base + k < n) { rowptr[base + k] = run; cursor[base + k] = run; }
    run += v[k];
  }
  if (n >= base && n <= base + 4) rowptr[n] = run;
}

__global__ void k_scatter(const int* __restrict__ src, const int* __restrict__ dst,
    int* __restrict__ cursor, int* __restrict__ esrc, int E) {
  int e = blockIdx.x * 256 + threadIdx.x;
  if (e < E) {
    int p = atomicAdd(&cursor[dst[e]], 1);
    esrc[p] = src[e];
  }
}

// ---------------- layout transform: row-major F -> planar FP ----------------
__global__ __launch_bounds__(256) void k_to_planar(const float* __restrict__ F,
    float* __restrict__ FP, int N) {
  int n = blockIdx.x * 4 + (threadIdx.x >> 6);
  int ic = threadIdx.x & 63;
#pragma unroll
  for (int q = 0; q < 4; ++q) {
    int col = q * 64 + ic;
    FP[((size_t)(col >> 4) * N + n) * 16 + (col & 15)] = F[(size_t)n * 256 + col];
  }
}

// ---------------- XCD-pinned planar aggregation v3: LDS-staged indices + float4 gathers ----
// XCD x drains plane x then x+8 (3.2 MB concurrent < 4 MB L2). Per item: stage rowptr+esrc
// slice into LDS (nontemporal, streaming), then 16-edge x 16-col float4 gathers from the
// L2-pinned plane. Work stealing guarantees completion under any block->XCD mapping.
__global__ __launch_bounds__(256) void k_aggp(const float* __restrict__ src,
    const int* __restrict__ rowptr, const int* __restrict__ esrc,
    float* __restrict__ out, int N, int* __restrict__ qctr, int rowmajor) {
  __shared__ int s_item;
  __shared__ int s_rp[NPI + 1];
  __shared__ int s_idx[MAXE];
  const int xcd = get_xcc_id();
  const int tid = threadIdx.x;
  const int lane = tid & 63;
  const int wv = tid >> 6;
  const int cl = lane & 3;     // float4 column group (cols cl*4..cl*4+3)
  const int es = lane >> 2;    // edge slot 0..15
  const int items_per_plane = (N + NPI - 1) / NPI;
  const int items_per_xcd = 2 * items_per_plane;
  const size_t rstride = rowmajor ? 64 : 4;   // node stride in float4 units

  for (int pass = 0; pass < 9; ++pass) {
    int q = (pass == 0) ? xcd : (pass - 1);
    if (pass > 0 && q == xcd) continue;
    while (true) {
      if (tid == 0) s_item = atomicAdd(&qctr[q], 1);
      __syncthreads();               // also fences previous item's LDS use
      int item = s_item;
      __syncthreads();
      if (item >= items_per_xcd) break;
      int sub = (item >= items_per_plane) ? 1 : 0;
      int ig = item - sub * items_per_plane;
      int plane = q + 8 * sub;
      int nbase = ig * NPI;
      int ncnt = min(NPI, N - nbase);
      if (tid <= ncnt) s_rp[tid] = rowptr[nbase + tid];
      __syncthreads();
      int ebeg = s_rp[0], eend = s_rp[ncnt];
      int ecnt = eend - ebeg;
      bool staged = (ecnt <= MAXE);
      if (staged)
        for (int t = tid; t < ecnt; t += 256)
          s_idx[t] = __builtin_nontemporal_load(&esrc[ebeg + t]);
      __syncthreads();
      const float4* pb = rowmajor ? ((const float4*)src + plane * 4 + cl)
                                  : ((const float4*)(src + (size_t)plane * N * 16) + cl);
      for (int n = wv; n < ncnt; n += 4) {
        int beg = s_rp[n] - ebeg, end = s_rp[n + 1] - ebeg;
        float4 a0 = {0,0,0,0}, a1 = {0,0,0,0};
        int e = beg + es;
        if (staged) {
          for (; e + 16 < end; e += 32) {
            int i0 = s_idx[e], i1 = s_idx[e + 16];
            float4 v0 = pb[(size_t)i0 * rstride];
            float4 v1 = pb[(size_t)i1 * rstride];
            a0.x += v0.x; a0.y += v0.y; a0.z += v0.z; a0.w += v0.w;
            a1.x += v1.x; a1.y += v1.y; a1.z += v1.z; a1.w += v1.w;
          }
          if (e < end) {
            float4 v = pb[(size_t)s_idx[e] * rstride];
            a0.x += v.x; a0.y += v.y; a0.z += v.z; a0.w += v.w;
          }
        } else {
          for (; e < end; e += 16) {
            float4 v = pb[(size_t)esrc[ebeg + e] * rstride];
            a0.x += v.x; a0.y += v.y; a0.z += v.z; a0.w += v.w;
          }
        }
        a0.x += a1.x; a0.y += a1.y; a0.z += a1.z; a0.w += a1.w;
#pragma unroll
        for (int off = 4; off <= 32; off <<= 1) {
          a0.x += __shfl_down(a0.x, off);
          a0.y += __shfl_down(a0.y, off);
          a0.z += __shfl_down(a0.z, off);
          a0.w += __shfl_down(a0.w, off);
        }
        if (lane < 4) {
          fv4* op = (fv4*)(out + ((size_t)plane * N + (nbase + n)) * 16);
          fv4 r; r.x = a0.x; r.y = a0.y; r.z = a0.z; r.w = a0.w;
          __builtin_nontemporal_store(r, op + lane);
        }
      }
    }
  }
}

// ---------------- scalar aggregation ----------------
__global__ void k_deg(const int* __restrict__ rowptr, float* __restrict__ out, int n) {
  int v = blockIdx.x * 256 + threadIdx.x;
  if (v < n) out[v] = (float)(rowptr[v + 1] - rowptr[v]);
}

__global__ __launch_bounds__(256) void k_aggv(const float* __restrict__ in,
    const int* __restrict__ rowptr, const int* __restrict__ esrc,
    float* __restrict__ out, int n) {
  int wid = ((blockIdx.x * 256) + threadIdx.x) >> 6;
  int lane = threadIdx.x & 63;
  if (wid >= n) return;
  int beg = rowptr[wid], end = rowptr[wid + 1];
  float s = 0.f;
  for (int e = beg + lane; e < end; e += 64) s += in[esrc[e]];
  for (int off = 32; off; off >>= 1) s += __shfl_down(s, off);
  if (lane == 0) out[wid] = s;
}

// ---------------- Gram on planar inputs ----------------
__global__ __launch_bounds__(256) void k_gram(const float* __restrict__ Xm,
    const float* __restrict__ Ym, float* __restrict__ partial, int N) {
  __shared__ float Xs[16][132];
  __shared__ float Ys[16][132];
  int tid = threadIdx.x;
  int i0 = blockIdx.x * 128, j0 = blockIdx.y * 128;
  int z = blockIdx.z;
  int chunk = (N + GRAM_KS - 1) / GRAM_KS;
  int rb = z * chunk, re = min(N, rb + chunk);
  int lk = tid >> 4;
  int tj = tid & 15;
  int lc = tj * 8;
  int ti = lk;
  float acc[8][8] = {};
  for (int rr = rb; rr < re; rr += 16) {
    int r = rr + lk;
    float4 a0 = {0,0,0,0}, a1 = {0,0,0,0}, b0 = {0,0,0,0}, b1 = {0,0,0,0};
    if (r < re) {
      int Cx = i0 + lc, Cy = j0 + lc;
      const float* xp = Xm + ((size_t)(Cx >> 4) * N + r) * 16 + (Cx & 15);
      const float* yp = Ym + ((size_t)(Cy >> 4) * N + r) * 16 + (Cy & 15);
      a0 = *(const float4*)xp; a1 = *(const float4*)(xp + 4);
      b0 = *(const float4*)yp; b1 = *(const float4*)(yp + 4);
    }
    *(float4*)&Xs[lk][lc] = a0; *(float4*)&Xs[lk][lc + 4] = a1;
    *(float4*)&Ys[lk][lc] = b0; *(float4*)&Ys[lk][lc + 4] = b1;
    __syncthreads();
#pragma unroll
    for (int k = 0; k < 16; ++k) {
      float av[8], bv[8];
      *(float4*)&av[0] = *(const float4*)&Xs[k][ti * 4];
      *(float4*)&av[4] = *(const float4*)&Xs[k][64 + ti * 4];
      *(float4*)&bv[0] = *(const float4*)&Ys[k][tj * 4];
      *(float4*)&bv[4] = *(const float4*)&Ys[k][64 + tj * 4];
#pragma unroll
      for (int i = 0; i < 8; ++i)
#pragma unroll
        for (int j = 0; j < 8; ++j) acc[i][j] += av[i] * bv[j];
    }
    __syncthreads();
  }
  float* pout = partial + (size_t)z * 65536;
#pragma unroll
  for (int i = 0; i < 8; ++i) {
    int row = i0 + ((i < 4) ? (ti * 4 + i) : (64 + ti * 4 + i - 4));
#pragma unroll
    for (int j = 0; j < 8; j += 4) {
      int col = j0 + ((j < 4) ? (tj * 4 + j) : (64 + tj * 4 + j - 4));
      *(float4*)(pout + (size_t)row * 256 + col) = *(float4*)&acc[i][j];
    }
  }
}

__global__ void k_gram_reduce(const float* __restrict__ partial, float* __restrict__ C) {
  int idx = blockIdx.x * 256 + threadIdx.x;
  float s = 0.f;
  for (int z = 0; z < GRAM_KS; ++z) s += partial[(size_t)z * 65536 + idx];
  C[idx] = s;
}

// ---------------- weighted column sums (planar G) ----------------
__global__ __launch_bounds__(256) void k_matvec3(const float* __restrict__ G,
    const float* __restrict__ wA, const float* __restrict__ wB,
    float* outA, float* outB, float* outS, int n) {
  int f = threadIdx.x;
  size_t pbase = ((size_t)(f >> 4) * n) * 16 + (f & 15);
  float sA = 0.f, sB = 0.f, sS = 0.f;
  for (int r = blockIdx.x; r < n; r += gridDim.x) {
    float v = G[pbase + (size_t)r * 16];
    if (wA) sA += v * wA[r];
    if (wB) sB += v * wB[r];
    sS += v;
  }
  if (outA) atomicAdd(&outA[f], sA);
  if (outB) atomicAdd(&outB[f], sB);
  atomicAdd(&outS[f], sS);
}

// ---------------- 8 scalar reductions over d/e vectors ----------------
__global__ __launch_bounds__(256) void k_dots(const float* __restrict__ d1,
    const float* __restrict__ e1, const float* __restrict__ d2,
    const float* __restrict__ e2, float* scal, int n) {
  int i = blockIdx.x * 256 + threadIdx.x;
  float a = 0, b = 0, c = 0, d = 0;
  if (i < n) { a = d1[i]; b = e1[i]; c = d2[i]; d = e2[i]; }
  float v[8] = { b * d, b * c, b, a * d, a * c, a, d, c };
#pragma unroll
  for (int j = 0; j < 8; ++j) {
    float x = v[j];
    for (int off = 32; off; off >>= 1) x += __shfl_down(x, off);
    v[j] = x;
  }
  if ((threadIdx.x & 63) == 0)
#pragma unroll
    for (int j = 0; j < 8; ++j) atomicAdd(&scal[j], v[j]);
}

// ---------------- t_j = w_j^T C w_j ; mv_j = w_j . m_raw ----------------
__global__ __launch_bounds__(256) void k_quad(const float* __restrict__ C,
    const float* __restrict__ W1, const float* __restrict__ m_raw,
    float* __restrict__ t, float* __restrict__ mv) {
  __shared__ float w[256];
  __shared__ float r1[256], r2[256];
  int j = blockIdx.x, tid = threadIdx.x;
  w[tid] = W1[j * 256 + tid];
  __syncthreads();
  float v = 0.f;
  for (int k = 0; k < 256; ++k) v += w[k] * C[k * 256 + tid];
  r1[tid] = v * w[tid];
  r2[tid] = w[tid] * m_raw[tid];
  __syncthreads();
  for (int off = 128; off; off >>= 1) {
    if (tid < off) { r1[tid] += r1[tid + off]; r2[tid] += r2[tid + off]; }
    __syncthreads();
  }
  if (tid == 0) { t[j] = r1[0]; mv[j] = r2[0]; }
}

// ---------------- BN coefficients + x = W3 W2 c, y = W3 b2 ----------------
__global__ __launch_bounds__(256) void k_bncoef(const float* __restrict__ t,
    const float* __restrict__ mv, const float* __restrict__ b1,
    const float* __restrict__ gamma, const float* __restrict__ beta,
    const float* __restrict__ W2, const float* __restrict__ W3,
    const float* __restrict__ b2, float* Dv, float* xv, float* yv, int n) {
  __shared__ float c[256], u[256];
  int j = threadIdx.x;
  float invn = 1.f / (float)n;
  float mean = mv[j] * invn + b1[j];
  float E2 = t[j] * invn + 2.f * b1[j] * mv[j] * invn + b1[j] * b1[j];
  float var = E2 - mean * mean;
  float D = gamma[j] * rsqrtf(var + 1e-5f);
  Dv[j] = D;
  c[j] = D * (b1[j] - mean) + beta[j];
  __syncthreads();
  float uu = 0.f;
  for (int k = 0; k < 256; ++k) uu += W2[j * 256 + k] * c[k];
  u[j] = uu;
  __syncthreads();
  float xx = 0.f, yy = 0.f;
  for (int k = 0; k < 256; ++k) {
    xx += W3[j * 256 + k] * u[k];
    yy += W3[j * 256 + k] * b2[k];
  }
  xv[j] = xx;
  yv[j] = yy;
}

// ---------------- small 256x256 matmul ----------------
__global__ __launch_bounds__(256) void k_mm_small(float* __restrict__ Cm,
    const float* __restrict__ A, const float* __restrict__ B,
    const float* __restrict__ s, int transA, int transB, int accum) {
  __shared__ float a[256];
  int i = blockIdx.x, j = threadIdx.x;
  float av = transA ? A[j * 256 + i] : A[i * 256 + j];
  a[j] = s ? av * s[j] : av;
  __syncthreads();
  float acc = 0.f;
  if (transB) {
    for (int k = 0; k < 256; ++k) acc += a[k] * B[j * 256 + k];
  } else {
    for (int k = 0; k < 256; ++k) acc += a[k] * B[k * 256 + j];
  }
  if (accum) Cm[i * 256 + j] += acc;
  else Cm[i * 256 + j] = acc;
}

// ---------------- C (+)= u1 v1^T + u2 v2^T + u3 v3^T ----------------
__global__ void k_r1x3(float* __restrict__ C, const float* __restrict__ u1,
    const float* __restrict__ v1, const float* __restrict__ u2,
    const float* __restrict__ v2, const float* __restrict__ u3,
    const float* __restrict__ v3, int accum) {
  int i = blockIdx.x, j = threadIdx.x;
  float val = u1[i] * v1[j] + u2[i] * v2[j] + u3[i] * v3[j];
  if (accum) C[i * 256 + j] += val;
  else C[i * 256 + j] = val;
}

__global__ void k_mixvec(const float* __restrict__ scal, const float* __restrict__ x2,
    const float* __restrict__ yv, const float* __restrict__ b3,
    float* s1, float* s2, float* s3, float fN) {
  int j = threadIdx.x;
  s1[j] = scal[0] * x2[j] + scal[1] * yv[j] + scal[2] * b3[j];
  s2[j] = scal[3] * x2[j] + scal[4] * yv[j] + scal[5] * b3[j];
  s3[j] = scal[6] * x2[j] + scal[7] * yv[j] + fN * b3[j];
}

extern "C" void kernel_launch(void* const* d_in, const int* in_sizes, int n_in,
                              void* d_out, int out_size, void* d_ws, size_t ws_size,
                              hipStream_t stream) {
  const float* feature = (const float*)d_in[0];
  const int* src1 = (const int*)d_in[1];
  const int* dst1 = (const int*)d_in[2];
  const int* src2 = (const int*)d_in[3];
  const int* dst2 = (const int*)d_in[4];
  const float* W1 = (const float*)d_in[5];
  const float* b1 = (const float*)d_in[6];
  const float* W2 = (const float*)d_in[7];
  const float* b2 = (const float*)d_in[8];
  const float* W3 = (const float*)d_in[9];
  const float* b3 = (const float*)d_in[10];
  const float* gamma = (const float*)d_in[11];
  const float* beta = (const float*)d_in[12];
  const int N = in_sizes[0] / FDIM;
  const int E = in_sizes[1];
  float* out = (float*)d_out;

  // ---- workspace layout ----
  float* X = (float*)d_ws;
  size_t NF = (size_t)N * FDIM;
  float* Y = X + NF;
  float* G2A = Y + NF;
  int* rowptr = (int*)(G2A + NF);
  int* cursor = rowptr + (N + 1);
  int* esrc = cursor + N;
  float* vtmp = (float*)(esrc + E);
  float* d1 = vtmp + N; float* e1 = d1 + N; float* d2 = e1 + N; float* e2 = d2 + N;
  float* C = e2 + N;
  float* m_raw = C + 65536;
  float* tq = m_raw + 256; float* mv = tq + 256;
  float* Dv = mv + 256; float* x1 = Dv + 256; float* x2 = x1 + 256; float* yv = x2 + 256;
  float* Q = yv + 256; float* R1 = Q + 65536; float* R2 = R1 + 65536;
  float* Z = R2 + 65536; float* K1 = Z + 65536; float* Lm = K1 + 65536;
  float* p1 = Lm + 65536; float* p2 = p1 + 256; float* p3 = p2 + 256;
  float* q1 = p3 + 256; float* q2 = q1 + 256; float* q3 = q2 + 256;
  float* scal = q3 + 256;
  float* s1 = scal + 16; float* s2 = s1 + 256; float* s3 = s2 + 256;
  int* blksum = (int*)(s3 + 256);
  int* blkoff = blksum + 1024;
  int* qctr = blkoff + 1024;          // 12 dispatches x 8 XCD queues
  float* FP = (float*)(qctr + 128);
  float* partial = X;   // GRAM_KS*65536 floats <= NF; X dead at gram time

  size_t need = (size_t)((char*)(FP + NF) - (char*)d_ws);
  int havePlanar = (ws_size >= need) ? 1 : 0;

  const int eb = (E + 255) / 256;
  const int nb = (N + 255) / 256;
  const int aggb = (N + 3) / 4;
  const int nblk = (N + 1023) / 1024;

  hipMemsetAsync(qctr, 0, 128 * sizeof(int), stream);
  int agg_idx = 0;

  auto build = [&](const int* s_, const int* d_) {
    hipMemsetAsync(cursor, 0, (size_t)N * sizeof(int), stream);
    k_hist<<<eb, 256, 0, stream>>>(d_, cursor, E);
    k_blksum<<<nblk, 256, 0, stream>>>(cursor, blksum, N);
    k_blkscan<<<1, 64, 0, stream>>>(blksum, blkoff, nblk);
    k_scan_blk<<<nblk, 256, 0, stream>>>(cursor, blkoff, rowptr, cursor, N);
    k_scatter<<<eb, 256, 0, stream>>>(s_, d_, cursor, esrc, E);
  };
  auto agg = [&](const float* in, float* o, int rowmajor) {
    k_aggp<<<2048, 256, 0, stream>>>(in, rowptr, esrc, o, N, qctr + 8 * agg_idx, rowmajor);
    agg_idx++;
  };
  auto gram = [&](const float* A_, const float* B_, float* Cout) {
    k_gram<<<dim3(2, 2, GRAM_KS), 256, 0, stream>>>(A_, B_, partial, N);
    k_gram_reduce<<<256, 256, 0, stream>>>(partial, Cout);
  };

  if (havePlanar) k_to_planar<<<(N + 3) / 4, 256, 0, stream>>>(feature, FP, N);

  auto do_branch = [&](const int* s_, const int* d_, float* G2dst,
                       float* dvec, float* evec, float* xvec, float* Rdst) {
    build(s_, d_);
    if (havePlanar) agg(FP, X, 0); else agg(feature, X, 1);
    agg(X, Y, 0);                               // Y = G0 (planar)
    gram(Y, Y, C);                              // C = G0^T G0
    hipMemsetAsync(m_raw, 0, 256 * sizeof(float), stream);
    k_matvec3<<<512, 256, 0, stream>>>(Y, nullptr, nullptr, nullptr, nullptr, m_raw, N);
    k_quad<<<256, 256, 0, stream>>>(C, W1, m_raw, tq, mv);
    k_bncoef<<<1, 256, 0, stream>>>(tq, mv, b1, gamma, beta, W2, W3, b2, Dv, xvec, yv, N);
    k_mm_small<<<256, 256, 0, stream>>>(Q, W1, W2, Dv, 1, 1, 0);
    k_mm_small<<<256, 256, 0, stream>>>(Rdst, Q, W3, nullptr, 0, 1, 0);
    k_deg<<<nb, 256, 0, stream>>>(rowptr, vtmp, N);
    k_aggv<<<aggb, 256, 0, stream>>>(vtmp, rowptr, esrc, dvec, N);   // d = A^2 1
    k_aggv<<<aggb, 256, 0, stream>>>(dvec, rowptr, esrc, vtmp, N);
    k_aggv<<<aggb, 256, 0, stream>>>(vtmp, rowptr, esrc, evec, N);   // e = A^4 1
    agg(Y, X, 0); agg(X, Y, 0);                 // Y = G1
    agg(Y, X, 0); agg(X, G2dst, 0);             // G2
  };

  do_branch(src1, dst1, G2A, d1, e1, x1, R1);
  do_branch(src2, dst2, Y, d2, e2, x2, R2);

  // ---- final assembly ----
  hipMemsetAsync(p1, 0, (6 * 256 + 16) * sizeof(float), stream);
  gram(G2A, Y, Z);                                                // Z = G2_1^T G2_2
  k_matvec3<<<512, 256, 0, stream>>>(G2A, e2, d2, p1, p2, p3, N);
  k_matvec3<<<512, 256, 0, stream>>>(Y, e1, d1, q1, q2, q3, N);
  k_dots<<<nb, 256, 0, stream>>>(d1, e1, d2, e2, scal, N);

  k_mm_small<<<256, 256, 0, stream>>>(K1, Z, R2, nullptr, 0, 0, 0);
  k_r1x3<<<256, 256, 0, stream>>>(K1, p1, x2, p2, yv, p3, b3, 1);
  k_r1x3<<<256, 256, 0, stream>>>(Lm, x1, q1, yv, q2, b3, q3, 0);
  k_mm_small<<<256, 256, 0, stream>>>(out, R1, K1, nullptr, 1, 0, 0);
  k_mm_small<<<256, 256, 0, stream>>>(out, Lm, R2, nullptr, 0, 0, 1);
  k_mixvec<<<1, 256, 0, stream>>>(scal, x2, yv, b3, s1, s2, s3, (float)N);
  k_r1x3<<<256, 256, 0, stream>>>(out, x1, s1, yv, s2, b3, s3, 1);
}

// Round 7
// 2498.002 us; speedup vs baseline: 2.8650x; 2.0972x over previous
//
#include <hip/hip_runtime.h>

#define FDIM 256
#define GRAM_KS 192

// ---------------- CSR build ----------------
__global__ void k_hist(const int* __restrict__ dst, int* __restrict__ deg, int E) {
  int e = blockIdx.x * 256 + threadIdx.x;
  if (e < E) atomicAdd(&deg[dst[e]], 1);
}

__global__ __launch_bounds__(256) void k_blksum(const int* __restrict__ deg,
    int* __restrict__ blksum, int n) {
  int b = blockIdx.x, tid = threadIdx.x;
  int base = b * 1024 + tid * 4;
  int s = 0;
#pragma unroll
  for (int k = 0; k < 4; ++k) if (base + k < n) s += deg[base + k];
  for (int off = 32; off; off >>= 1) s += __shfl_down(s, off);
  __shared__ int ws4[4];
  if ((tid & 63) == 0) ws4[tid >> 6] = s;
  __syncthreads();
  if (tid == 0) blksum[b] = ws4[0] + ws4[1] + ws4[2] + ws4[3];
}

__global__ void k_blkscan(const int* __restrict__ blksum, int* __restrict__ blkoff, int nblk) {
  int lane = threadIdx.x;
  int carry = 0;
  for (int base = 0; base < nblk; base += 64) {
    int v = (base + lane < nblk) ? blksum[base + lane] : 0;
    int x = v;
    for (int off = 1; off < 64; off <<= 1) { int y = __shfl_up(x, off); if (lane >= off) x += y; }
    if (base + lane < nblk) blkoff[base + lane] = carry + x - v;
    carry += __shfl(x, 63);
  }
}

__global__ __launch_bounds__(256) void k_scan_blk(const int* __restrict__ deg,
    const int* __restrict__ blkoff, int* __restrict__ rowptr, int* __restrict__ cursor, int n) {
  int b = blockIdx.x, tid = threadIdx.x;
  int base = b * 1024 + tid * 4;
  int v[4];
#pragma unroll
  for (int k = 0; k < 4; ++k) v[k] = (base + k < n) ? deg[base + k] : 0;
  int s = v[0] + v[1] + v[2] + v[3];
  int lane = tid & 63, w = tid >> 6;
  int x = s;
  for (int off = 1; off < 64; off <<= 1) { int y = __shfl_up(x, off); if (lane >= off) x += y; }
  __shared__ int wsum[4];
  if (lane == 63) wsum[w] = x;
  __syncthreads();
  int wadd = 0;
  for (int i = 0; i < w; ++i) wadd += wsum[i];
  int run = blkoff[b] + wadd + x - s;
#pragma unroll
  for (int k = 0; k < 4; ++k) {
    if (base + k < n) { rowptr[base + k] = run; cursor[base + k] = run; }
    run += v[k];
  }
  if (n >= base && n <= base + 4) rowptr[n] = run;
}

__global__ void k_scatter(const int* __restrict__ src, const int* __restrict__ dst,
    int* __restrict__ cursor, int* __restrict__ esrc, int E) {
  int e = blockIdx.x * 256 + threadIdx.x;
  if (e < E) {
    int p = atomicAdd(&cursor[dst[e]], 1);
    esrc[p] = src[e];
  }
}

// ---------------- feature aggregation: row-major full-row gathers ----------------
// One wave per node (grid-stride), lane = float4 column group. Unroll-4 main loop for
// 4 outstanding 1KB row loads; clean scalar remainder (no wasted loads). Optional fused
// column sums (plain / weighted) accumulated in registers -> LDS -> per-block atomics.
__global__ __launch_bounds__(256) void k_agg(const float* __restrict__ h,
    const int* __restrict__ rowptr, const int* __restrict__ esrc,
    float* __restrict__ out, int n,
    const float* __restrict__ wA, const float* __restrict__ wB,
    float* __restrict__ sumA, float* __restrict__ sumB, float* __restrict__ sumP) {
  int lane = threadIdx.x & 63;
  int wv = threadIdx.x >> 6;
  int gw = blockIdx.x * 4 + wv;
  int nw = gridDim.x * 4;
  const float4* hv = (const float4*)h;
  float4* ov = (float4*)out;
  float4 accP = {0,0,0,0}, accA = {0,0,0,0}, accB = {0,0,0,0};
  for (int node = gw; node < n; node += nw) {
    int beg = rowptr[node], end = rowptr[node + 1];
    float4 a0 = {0,0,0,0}, a1 = {0,0,0,0}, a2 = {0,0,0,0}, a3 = {0,0,0,0};
    int e = beg;
    for (; e + 4 <= end; e += 4) {
      int s0 = esrc[e], s1 = esrc[e + 1], s2 = esrc[e + 2], s3 = esrc[e + 3];
      float4 v0 = hv[(size_t)s0 * 64 + lane];
      float4 v1 = hv[(size_t)s1 * 64 + lane];
      float4 v2 = hv[(size_t)s2 * 64 + lane];
      float4 v3 = hv[(size_t)s3 * 64 + lane];
      a0.x += v0.x; a0.y += v0.y; a0.z += v0.z; a0.w += v0.w;
      a1.x += v1.x; a1.y += v1.y; a1.z += v1.z; a1.w += v1.w;
      a2.x += v2.x; a2.y += v2.y; a2.z += v2.z; a2.w += v2.w;
      a3.x += v3.x; a3.y += v3.y; a3.z += v3.z; a3.w += v3.w;
    }
    for (; e < end; ++e) {
      float4 v = hv[(size_t)esrc[e] * 64 + lane];
      a0.x += v.x; a0.y += v.y; a0.z += v.z; a0.w += v.w;
    }
    float4 r;
    r.x = (a0.x + a1.x) + (a2.x + a3.x);
    r.y = (a0.y + a1.y) + (a2.y + a3.y);
    r.z = (a0.z + a1.z) + (a2.z + a3.z);
    r.w = (a0.w + a1.w) + (a2.w + a3.w);
    ov[(size_t)node * 64 + lane] = r;
    if (sumP) { accP.x += r.x; accP.y += r.y; accP.z += r.z; accP.w += r.w; }
    if (sumA) {
      float wa = wA[node], wb = wB[node];
      accA.x += r.x * wa; accA.y += r.y * wa; accA.z += r.z * wa; accA.w += r.w * wa;
      accB.x += r.x * wb; accB.y += r.y * wb; accB.z += r.z * wb; accB.w += r.w * wb;
    }
  }
  if (sumP || sumA) {
    __shared__ float red[4][256];
    int tid = threadIdx.x;
    if (sumP) {
      *(float4*)&red[wv][lane * 4] = accP;
      __syncthreads();
      float v = red[0][tid] + red[1][tid] + red[2][tid] + red[3][tid];
      atomicAdd(&sumP[tid], v);
      __syncthreads();
    }
    if (sumA) {
      *(float4*)&red[wv][lane * 4] = accA;
      __syncthreads();
      float v = red[0][tid] + red[1][tid] + red[2][tid] + red[3][tid];
      atomicAdd(&sumA[tid], v);
      __syncthreads();
      *(float4*)&red[wv][lane * 4] = accB;
      __syncthreads();
      float v2 = red[0][tid] + red[1][tid] + red[2][tid] + red[3][tid];
      atomicAdd(&sumB[tid], v2);
    }
  }
}

// ---------------- scalar aggregation: 16 lanes per node ----------------
__global__ void k_deg(const int* __restrict__ rowptr, float* __restrict__ out, int n) {
  int v = blockIdx.x * 256 + threadIdx.x;
  if (v < n) out[v] = (float)(rowptr[v + 1] - rowptr[v]);
}

__global__ __launch_bounds__(256) void k_aggv(const float* __restrict__ in,
    const int* __restrict__ rowptr, const int* __restrict__ esrc,
    float* __restrict__ out, int n) {
  int t = blockIdx.x * 256 + threadIdx.x;
  int node = t >> 4;
  int sl = t & 15;
  if (node >= n) return;
  int beg = rowptr[node], end = rowptr[node + 1];
  float s = 0.f;
  for (int e = beg + sl; e < end; e += 16) s += in[esrc[e]];
#pragma unroll
  for (int off = 8; off; off >>= 1) s += __shfl_down(s, off, 16);
  if (sl == 0) out[node] = s;
}

// ---------------- Gram (row-major): partial[z] = X_chunk^T Y_chunk ----------------
// 128x128 tile, 256 thr, 8x8 acc, split fragments {t*4, 64+t*4}, LDS rows padded to 132.
__global__ __launch_bounds__(256) void k_gram(const float* __restrict__ Xm,
    const float* __restrict__ Ym, float* __restrict__ partial, int N) {
  __shared__ float Xs[16][132];
  __shared__ float Ys[16][132];
  int tid = threadIdx.x;
  int i0 = blockIdx.x * 128, j0 = blockIdx.y * 128;
  int z = blockIdx.z;
  int chunk = (N + GRAM_KS - 1) / GRAM_KS;
  int rb = z * chunk, re = min(N, rb + chunk);
  int lk = tid >> 4;          // k row 0..15
  int tj = tid & 15;
  int lc = tj * 8;
  int ti = lk;
  float acc[8][8] = {};
  for (int rr = rb; rr < re; rr += 16) {
    int r = rr + lk;
    float4 a0 = {0,0,0,0}, a1 = {0,0,0,0}, b0 = {0,0,0,0}, b1 = {0,0,0,0};
    if (r < re) {
      const float* xp = Xm + (size_t)r * 256 + i0 + lc;
      const float* yp = Ym + (size_t)r * 256 + j0 + lc;
      a0 = *(const float4*)xp; a1 = *(const float4*)(xp + 4);
      b0 = *(const float4*)yp; b1 = *(const float4*)(yp + 4);
    }
    *(float4*)&Xs[lk][lc] = a0; *(float4*)&Xs[lk][lc + 4] = a1;
    *(float4*)&Ys[lk][lc] = b0; *(float4*)&Ys[lk][lc + 4] = b1;
    __syncthreads();
#pragma unroll
    for (int k = 0; k < 16; ++k) {
      float av[8], bv[8];
      *(float4*)&av[0] = *(const float4*)&Xs[k][ti * 4];
      *(float4*)&av[4] = *(const float4*)&Xs[k][64 + ti * 4];
      *(float4*)&bv[0] = *(const float4*)&Ys[k][tj * 4];
      *(float4*)&bv[4] = *(const float4*)&Ys[k][64 + tj * 4];
#pragma unroll
      for (int i = 0; i < 8; ++i)
#pragma unroll
        for (int j = 0; j < 8; ++j) acc[i][j] += av[i] * bv[j];
    }
    __syncthreads();
  }
  float* pout = partial + (size_t)z * 65536;
#pragma unroll
  for (int i = 0; i < 8; ++i) {
    int row = i0 + ((i < 4) ? (ti * 4 + i) : (64 + ti * 4 + i - 4));
#pragma unroll
    for (int j = 0; j < 8; j += 4) {
      int col = j0 + ((j < 4) ? (tj * 4 + j) : (64 + tj * 4 + j - 4));
      *(float4*)(pout + (size_t)row * 256 + col) = *(float4*)&acc[i][j];
    }
  }
}

__global__ void k_gram_reduce(const float* __restrict__ partial, float* __restrict__ C) {
  int idx = blockIdx.x * 256 + threadIdx.x;
  float s = 0.f;
  for (int z = 0; z < GRAM_KS; ++z) s += partial[(size_t)z * 65536 + idx];
  C[idx] = s;
}

// ---------------- 8 scalar reductions over d/e vectors ----------------
__global__ __launch_bounds__(256) void k_dots(const float* __restrict__ d1,
    const float* __restrict__ e1, const float* __restrict__ d2,
    const float* __restrict__ e2, float* scal, int n) {
  int i = blockIdx.x * 256 + threadIdx.x;
  float a = 0, b = 0, c = 0, d = 0;
  if (i < n) { a = d1[i]; b = e1[i]; c = d2[i]; d = e2[i]; }
  float v[8] = { b * d, b * c, b, a * d, a * c, a, d, c };
#pragma unroll
  for (int j = 0; j < 8; ++j) {
    float x = v[j];
    for (int off = 32; off; off >>= 1) x += __shfl_down(x, off);
    v[j] = x;
  }
  if ((threadIdx.x & 63) == 0)
#pragma unroll
    for (int j = 0; j < 8; ++j) atomicAdd(&scal[j], v[j]);
}

// ---------------- t_j = w_j^T C w_j ; mv_j = w_j . m_raw ----------------
__global__ __launch_bounds__(256) void k_quad(const float* __restrict__ C,
    const float* __restrict__ W1, const float* __restrict__ m_raw,
    float* __restrict__ t, float* __restrict__ mv) {
  __shared__ float w[256];
  __shared__ float r1[256], r2[256];
  int j = blockIdx.x, tid = threadIdx.x;
  w[tid] = W1[j * 256 + tid];
  __syncthreads();
  float v = 0.f;
  for (int k = 0; k < 256; ++k) v += w[k] * C[k * 256 + tid];
  r1[tid] = v * w[tid];
  r2[tid] = w[tid] * m_raw[tid];
  __syncthreads();
  for (int off = 128; off; off >>= 1) {
    if (tid < off) { r1[tid] += r1[tid + off]; r2[tid] += r2[tid + off]; }
    __syncthreads();
  }
  if (tid == 0) { t[j] = r1[0]; mv[j] = r2[0]; }
}

// ---------------- BN coefficients + x = W3 W2 c, y = W3 b2 ----------------
__global__ __launch_bounds__(256) void k_bncoef(const float* __restrict__ t,
    const float* __restrict__ mv, const float* __restrict__ b1,
    const float* __restrict__ gamma, const float* __restrict__ beta,
    const float* __restrict__ W2, const float* __restrict__ W3,
    const float* __restrict__ b2, float* Dv, float* xv, float* yv, int n) {
  __shared__ float c[256], u[256];
  int j = threadIdx.x;
  float invn = 1.f / (float)n;
  float mean = mv[j] * invn + b1[j];
  float E2 = t[j] * invn + 2.f * b1[j] * mv[j] * invn + b1[j] * b1[j];
  float var = E2 - mean * mean;
  float D = gamma[j] * rsqrtf(var + 1e-5f);
  Dv[j] = D;
  c[j] = D * (b1[j] - mean) + beta[j];
  __syncthreads();
  float uu = 0.f;
  for (int k = 0; k < 256; ++k) uu += W2[j * 256 + k] * c[k];
  u[j] = uu;
  __syncthreads();
  float xx = 0.f, yy = 0.f;
  for (int k = 0; k < 256; ++k) {
    xx += W3[j * 256 + k] * u[k];
    yy += W3[j * 256 + k] * b2[k];
  }
  xv[j] = xx;
  yv[j] = yy;
}

// ---------------- small 256x256 matmul ----------------
__global__ __launch_bounds__(256) void k_mm_small(float* __restrict__ Cm,
    const float* __restrict__ A, const float* __restrict__ B,
    const float* __restrict__ s, int transA, int transB, int accum) {
  __shared__ float a[256];
  int i = blockIdx.x, j = threadIdx.x;
  float av = transA ? A[j * 256 + i] : A[i * 256 + j];
  a[j] = s ? av * s[j] : av;
  __syncthreads();
  float acc = 0.f;
  if (transB) {
    for (int k = 0; k < 256; ++k) acc += a[k] * B[j * 256 + k];
  } else {
    for (int k = 0; k < 256; ++k) acc += a[k] * B[k * 256 + j];
  }
  if (accum) Cm[i * 256 + j] += acc;
  else Cm[i * 256 + j] = acc;
}

// ---------------- C (+)= u1 v1^T + u2 v2^T + u3 v3^T ----------------
__global__ void k_r1x3(float* __restrict__ C, const float* __restrict__ u1,
    const float* __restrict__ v1, const float* __restrict__ u2,
    const float* __restrict__ v2, const float* __restrict__ u3,
    const float* __restrict__ v3, int accum) {
  int i = blockIdx.x, j = threadIdx.x;
  float val = u1[i] * v1[j] + u2[i] * v2[j] + u3[i] * v3[j];
  if (accum) C[i * 256 + j] += val;
  else C[i * 256 + j] = val;
}

__global__ void k_mixvec(const float* __restrict__ scal, const float* __restrict__ x2,
    const float* __restrict__ yv, const float* __restrict__ b3,
    float* s1, float* s2, float* s3, float fN) {
  int j = threadIdx.x;
  s1[j] = scal[0] * x2[j] + scal[1] * yv[j] + scal[2] * b3[j];
  s2[j] = scal[3] * x2[j] + scal[4] * yv[j] + scal[5] * b3[j];
  s3[j] = scal[6] * x2[j] + scal[7] * yv[j] + fN * b3[j];
}

extern "C" void kernel_launch(void* const* d_in, const int* in_sizes, int n_in,
                              void* d_out, int out_size, void* d_ws, size_t ws_size,
                              hipStream_t stream) {
  const float* feature = (const float*)d_in[0];
  const int* src1 = (const int*)d_in[1];
  const int* dst1 = (const int*)d_in[2];
  const int* src2 = (const int*)d_in[3];
  const int* dst2 = (const int*)d_in[4];
  const float* W1 = (const float*)d_in[5];
  const float* b1 = (const float*)d_in[6];
  const float* W2 = (const float*)d_in[7];
  const float* b2 = (const float*)d_in[8];
  const float* W3 = (const float*)d_in[9];
  const float* b3 = (const float*)d_in[10];
  const float* gamma = (const float*)d_in[11];
  const float* beta = (const float*)d_in[12];
  const int N = in_sizes[0] / FDIM;
  const int E = in_sizes[1];
  float* out = (float*)d_out;

  // ---- workspace layout ----
  float* X = (float*)d_ws;
  size_t NF = (size_t)N * FDIM;
  float* Y = X + NF;
  float* G2A = Y + NF;
  int* rowptr1 = (int*)(G2A + NF);
  int* rowptr2 = rowptr1 + (N + 1);
  int* cursor = rowptr2 + (N + 1);
  int* esrc1 = cursor + N;
  int* esrc2 = esrc1 + E;
  float* vtmp = (float*)(esrc2 + E);
  float* d1 = vtmp + N; float* e1 = d1 + N; float* d2 = e1 + N; float* e2 = d2 + N;
  float* C = e2 + N;
  float* m_raw = C + 65536;
  float* tq = m_raw + 256; float* mv = tq + 256;
  float* Dv = mv + 256; float* x1 = Dv + 256; float* x2 = x1 + 256; float* yv = x2 + 256;
  float* Q = yv + 256; float* R1 = Q + 65536; float* R2 = R1 + 65536;
  float* Z = R2 + 65536; float* K1 = Z + 65536; float* Lm = K1 + 65536;
  float* p1 = Lm + 65536; float* p2 = p1 + 256; float* p3 = p2 + 256;
  float* q1 = p3 + 256; float* q2 = q1 + 256; float* q3 = q2 + 256;
  float* scal = q3 + 256;
  float* s1 = scal + 16; float* s2 = s1 + 256; float* s3 = s2 + 256;
  int* blksum = (int*)(s3 + 256);
  int* blkoff = blksum + 1024;
  float* partial = X;   // GRAM_KS*65536 = 12.58M floats <= NF (12.8M); X dead at gram time

  const int eb = (E + 255) / 256;
  const int nb = (N + 255) / 256;
  const int avb = (N + 15) / 16;       // 16 threads per node
  const int nblk = (N + 1023) / 1024;
  const int AGG_BLOCKS = 2048;

  auto build = [&](const int* s_, const int* d_, int* rp, int* es) {
    hipMemsetAsync(cursor, 0, (size_t)N * sizeof(int), stream);
    k_hist<<<eb, 256, 0, stream>>>(d_, cursor, E);
    k_blksum<<<nblk, 256, 0, stream>>>(cursor, blksum, N);
    k_blkscan<<<1, 64, 0, stream>>>(blksum, blkoff, nblk);
    k_scan_blk<<<nblk, 256, 0, stream>>>(cursor, blkoff, rp, cursor, N);
    k_scatter<<<eb, 256, 0, stream>>>(s_, d_, cursor, es, E);
  };
  auto agg = [&](const float* in, float* o, const int* rp, const int* es,
                 const float* wA, const float* wB, float* sA, float* sB, float* sP) {
    k_agg<<<AGG_BLOCKS, 256, 0, stream>>>(in, rp, es, o, N, wA, wB, sA, sB, sP);
  };
  auto gram = [&](const float* A_, const float* B_, float* Cout) {
    k_gram<<<dim3(2, 2, GRAM_KS), 256, 0, stream>>>(A_, B_, partial, N);
    k_gram_reduce<<<256, 256, 0, stream>>>(partial, Cout);
  };

  // ---- build both CSRs + degree vectors up front ----
  build(src1, dst1, rowptr1, esrc1);
  build(src2, dst2, rowptr2, esrc2);
  hipMemsetAsync(p1, 0, (6 * 256 + 16) * sizeof(float), stream);  // p1..q3 + scal

  k_deg<<<nb, 256, 0, stream>>>(rowptr1, vtmp, N);
  k_aggv<<<avb, 256, 0, stream>>>(vtmp, rowptr1, esrc1, d1, N);    // d1 = A1^2 1
  k_aggv<<<avb, 256, 0, stream>>>(d1, rowptr1, esrc1, vtmp, N);
  k_aggv<<<avb, 256, 0, stream>>>(vtmp, rowptr1, esrc1, e1, N);    // e1 = A1^4 1
  k_deg<<<nb, 256, 0, stream>>>(rowptr2, vtmp, N);
  k_aggv<<<avb, 256, 0, stream>>>(vtmp, rowptr2, esrc2, d2, N);    // d2 = A2^2 1
  k_aggv<<<avb, 256, 0, stream>>>(d2, rowptr2, esrc2, vtmp, N);
  k_aggv<<<avb, 256, 0, stream>>>(vtmp, rowptr2, esrc2, e2, N);    // e2 = A2^4 1
  k_dots<<<nb, 256, 0, stream>>>(d1, e1, d2, e2, scal, N);

  auto do_branch = [&](const int* rp, const int* es, float* G2dst,
                       const float* wA, const float* wB,
                       float* sA, float* sB, float* sP, float* xvec, float* Rdst) {
    agg(feature, X, rp, es, 0, 0, 0, 0, 0);
    hipMemsetAsync(m_raw, 0, 256 * sizeof(float), stream);
    agg(X, Y, rp, es, 0, 0, 0, 0, m_raw);       // Y = G0, fused colsum
    gram(Y, Y, C);                              // C = G0^T G0 (partial aliases X)
    k_quad<<<256, 256, 0, stream>>>(C, W1, m_raw, tq, mv);
    k_bncoef<<<1, 256, 0, stream>>>(tq, mv, b1, gamma, beta, W2, W3, b2, Dv, xvec, yv, N);
    k_mm_small<<<256, 256, 0, stream>>>(Q, W1, W2, Dv, 1, 1, 0);     // Q = W1^T D W2^T
    k_mm_small<<<256, 256, 0, stream>>>(Rdst, Q, W3, nullptr, 0, 1, 0); // R = Q W3^T
    agg(Y, X, rp, es, 0, 0, 0, 0, 0);           // A^3 F
    agg(X, Y, rp, es, 0, 0, 0, 0, 0);           // A^4 F
    agg(Y, X, rp, es, 0, 0, 0, 0, 0);           // A^5 F
    agg(X, G2dst, rp, es, wA, wB, sA, sB, sP);  // G2 + fused weighted colsums
  };

  do_branch(rowptr1, esrc1, G2A, e2, d2, p1, p2, p3, x1, R1);
  do_branch(rowptr2, esrc2, Y, e1, d1, q1, q2, q3, x2, R2);  // branch-2 G2 in Y

  // ---- final assembly ----
  gram(G2A, Y, Z);                                                // Z = G2_1^T G2_2
  k_mm_small<<<256, 256, 0, stream>>>(K1, Z, R2, nullptr, 0, 0, 0);   // K1 = Z R2
  k_r1x3<<<256, 256, 0, stream>>>(K1, p1, x2, p2, yv, p3, b3, 1);
  k_r1x3<<<256, 256, 0, stream>>>(Lm, x1, q1, yv, q2, b3, q3, 0);
  k_mm_small<<<256, 256, 0, stream>>>(out, R1, K1, nullptr, 1, 0, 0); // out = R1^T K1
  k_mm_small<<<256, 256, 0, stream>>>(out, Lm, R2, nullptr, 0, 0, 1); // out += L R2
  k_mixvec<<<1, 256, 0, stream>>>(scal, x2, yv, b3, s1, s2, s3, (float)N);
  k_r1x3<<<256, 256, 0, stream>>>(out, x1, s1, yv, s2, b3, s3, 1);
}

// Round 8
// 2420.087 us; speedup vs baseline: 2.9572x; 1.0322x over previous
//
#include <hip/hip_runtime.h>

#define FDIM 256
#define GRAM_KS 192

// ---------------- CSR build ----------------
__global__ void k_hist(const int* __restrict__ dst, int* __restrict__ deg, int E) {
  int e = blockIdx.x * 256 + threadIdx.x;
  if (e < E) atomicAdd(&deg[dst[e]], 1);
}

__global__ __launch_bounds__(256) void k_blksum(const int* __restrict__ deg,
    int* __restrict__ blksum, int n) {
  int b = blockIdx.x, tid = threadIdx.x;
  int base = b * 1024 + tid * 4;
  int s = 0;
#pragma unroll
  for (int k = 0; k < 4; ++k) if (base + k < n) s += deg[base + k];
  for (int off = 32; off; off >>= 1) s += __shfl_down(s, off);
  __shared__ int ws4[4];
  if ((tid & 63) == 0) ws4[tid >> 6] = s;
  __syncthreads();
  if (tid == 0) blksum[b] = ws4[0] + ws4[1] + ws4[2] + ws4[3];
}

__global__ void k_blkscan(const int* __restrict__ blksum, int* __restrict__ blkoff, int nblk) {
  int lane = threadIdx.x;
  int carry = 0;
  for (int base = 0; base < nblk; base += 64) {
    int v = (base + lane < nblk) ? blksum[base + lane] : 0;
    int x = v;
    for (int off = 1; off < 64; off <<= 1) { int y = __shfl_up(x, off); if (lane >= off) x += y; }
    if (base + lane < nblk) blkoff[base + lane] = carry + x - v;
    carry += __shfl(x, 63);
  }
}

__global__ __launch_bounds__(256) void k_scan_blk(const int* __restrict__ deg,
    const int* __restrict__ blkoff, int* __restrict__ rowptr, int* __restrict__ cursor, int n) {
  int b = blockIdx.x, tid = threadIdx.x;
  int base = b * 1024 + tid * 4;
  int v[4];
#pragma unroll
  for (int k = 0; k < 4; ++k) v[k] = (base + k < n) ? deg[base + k] : 0;
  int s = v[0] + v[1] + v[2] + v[3];
  int lane = tid & 63, w = tid >> 6;
  int x = s;
  for (int off = 1; off < 64; off <<= 1) { int y = __shfl_up(x, off); if (lane >= off) x += y; }
  __shared__ int wsum[4];
  if (lane == 63) wsum[w] = x;
  __syncthreads();
  int wadd = 0;
  for (int i = 0; i < w; ++i) wadd += wsum[i];
  int run = blkoff[b] + wadd + x - s;
#pragma unroll
  for (int k = 0; k < 4; ++k) {
    if (base + k < n) { rowptr[base + k] = run; cursor[base + k] = run; }
    run += v[k];
  }
  if (n >= base && n <= base + 4) rowptr[n] = run;
}

__global__ void k_scatter(const int* __restrict__ src, const int* __restrict__ dst,
    int* __restrict__ cursor, int* __restrict__ esrc, int E) {
  int e = blockIdx.x * 256 + threadIdx.x;
  if (e < E) {
    int p = atomicAdd(&cursor[dst[e]], 1);
    esrc[p] = src[e];
  }
}

// ---------------- feature aggregation ----------------
// One wave per node, ONE-SHOT (no grid stride: wave turnover = MLP). Clean unroll-4:
// 4 outstanding 1KB row gathers in the main loop, scalar remainder (<=3, no wasted loads).
__global__ __launch_bounds__(256) void k_agg(const float* __restrict__ h,
    const int* __restrict__ rowptr, const int* __restrict__ esrc,
    float* __restrict__ out, int n) {
  int wid = ((blockIdx.x * 256) + threadIdx.x) >> 6;
  int lane = threadIdx.x & 63;
  if (wid >= n) return;
  int beg = rowptr[wid], end = rowptr[wid + 1];
  const float4* hv = (const float4*)h;
  float4 a0 = {0,0,0,0}, a1 = {0,0,0,0}, a2 = {0,0,0,0}, a3 = {0,0,0,0};
  int e = beg;
  for (; e + 4 <= end; e += 4) {
    int s0 = esrc[e], s1 = esrc[e + 1], s2 = esrc[e + 2], s3 = esrc[e + 3];
    float4 v0 = hv[(size_t)s0 * 64 + lane];
    float4 v1 = hv[(size_t)s1 * 64 + lane];
    float4 v2 = hv[(size_t)s2 * 64 + lane];
    float4 v3 = hv[(size_t)s3 * 64 + lane];
    a0.x += v0.x; a0.y += v0.y; a0.z += v0.z; a0.w += v0.w;
    a1.x += v1.x; a1.y += v1.y; a1.z += v1.z; a1.w += v1.w;
    a2.x += v2.x; a2.y += v2.y; a2.z += v2.z; a2.w += v2.w;
    a3.x += v3.x; a3.y += v3.y; a3.z += v3.z; a3.w += v3.w;
  }
  for (; e < end; ++e) {
    float4 v = hv[(size_t)esrc[e] * 64 + lane];
    a0.x += v.x; a0.y += v.y; a0.z += v.z; a0.w += v.w;
  }
  float4 r;
  r.x = (a0.x + a1.x) + (a2.x + a3.x);
  r.y = (a0.y + a1.y) + (a2.y + a3.y);
  r.z = (a0.z + a1.z) + (a2.z + a3.z);
  r.w = (a0.w + a1.w) + (a2.w + a3.w);
  ((float4*)out)[(size_t)wid * 64 + lane] = r;
}

// ---------------- scalar aggregation: 16 lanes per node ----------------
__global__ void k_deg(const int* __restrict__ rowptr, float* __restrict__ out, int n) {
  int v = blockIdx.x * 256 + threadIdx.x;
  if (v < n) out[v] = (float)(rowptr[v + 1] - rowptr[v]);
}

__global__ __launch_bounds__(256) void k_aggv(const float* __restrict__ in,
    const int* __restrict__ rowptr, const int* __restrict__ esrc,
    float* __restrict__ out, int n) {
  int t = blockIdx.x * 256 + threadIdx.x;
  int node = t >> 4;
  int sl = t & 15;
  if (node >= n) return;
  int beg = rowptr[node], end = rowptr[node + 1];
  float s = 0.f;
  for (int e = beg + sl; e < end; e += 16) s += in[esrc[e]];
#pragma unroll
  for (int off = 8; off; off >>= 1) s += __shfl_down(s, off, 16);
  if (sl == 0) out[node] = s;
}

// ---------------- Gram: partial[z] = X_chunk^T Y_chunk (128x128 tile) ----------------
__global__ __launch_bounds__(256) void k_gram(const float* __restrict__ Xm,
    const float* __restrict__ Ym, float* __restrict__ partial, int N) {
  __shared__ float Xs[16][132];
  __shared__ float Ys[16][132];
  int tid = threadIdx.x;
  int i0 = blockIdx.x * 128, j0 = blockIdx.y * 128;
  int z = blockIdx.z;
  int chunk = (N + GRAM_KS - 1) / GRAM_KS;
  int rb = z * chunk, re = min(N, rb + chunk);
  int lk = tid >> 4;
  int tj = tid & 15;
  int lc = tj * 8;
  int ti = lk;
  float acc[8][8] = {};
  for (int rr = rb; rr < re; rr += 16) {
    int r = rr + lk;
    float4 a0 = {0,0,0,0}, a1 = {0,0,0,0}, b0 = {0,0,0,0}, b1 = {0,0,0,0};
    if (r < re) {
      const float* xp = Xm + (size_t)r * 256 + i0 + lc;
      const float* yp = Ym + (size_t)r * 256 + j0 + lc;
      a0 = *(const float4*)xp; a1 = *(const float4*)(xp + 4);
      b0 = *(const float4*)yp; b1 = *(const float4*)(yp + 4);
    }
    *(float4*)&Xs[lk][lc] = a0; *(float4*)&Xs[lk][lc + 4] = a1;
    *(float4*)&Ys[lk][lc] = b0; *(float4*)&Ys[lk][lc + 4] = b1;
    __syncthreads();
#pragma unroll
    for (int k = 0; k < 16; ++k) {
      float av[8], bv[8];
      *(float4*)&av[0] = *(const float4*)&Xs[k][ti * 4];
      *(float4*)&av[4] = *(const float4*)&Xs[k][64 + ti * 4];
      *(float4*)&bv[0] = *(const float4*)&Ys[k][tj * 4];
      *(float4*)&bv[4] = *(const float4*)&Ys[k][64 + tj * 4];
#pragma unroll
      for (int i = 0; i < 8; ++i)
#pragma unroll
        for (int j = 0; j < 8; ++j) acc[i][j] += av[i] * bv[j];
    }
    __syncthreads();
  }
  float* pout = partial + (size_t)z * 65536;
#pragma unroll
  for (int i = 0; i < 8; ++i) {
    int row = i0 + ((i < 4) ? (ti * 4 + i) : (64 + ti * 4 + i - 4));
#pragma unroll
    for (int j = 0; j < 8; j += 4) {
      int col = j0 + ((j < 4) ? (tj * 4 + j) : (64 + tj * 4 + j - 4));
      *(float4*)(pout + (size_t)row * 256 + col) = *(float4*)&acc[i][j];
    }
  }
}

__global__ void k_gram_reduce(const float* __restrict__ partial, float* __restrict__ C) {
  int idx = blockIdx.x * 256 + threadIdx.x;
  float s = 0.f;
  for (int z = 0; z < GRAM_KS; ++z) s += partial[(size_t)z * 65536 + idx];
  C[idx] = s;
}

// ---------------- weighted column sums: outA=G^T wA, outB=G^T wB, outS=colsum G ----------------
__global__ __launch_bounds__(256) void k_matvec3(const float* __restrict__ G,
    const float* __restrict__ wA, const float* __restrict__ wB,
    float* outA, float* outB, float* outS, int n) {
  int f = threadIdx.x;
  float sA = 0.f, sB = 0.f, sS = 0.f;
  for (int r = blockIdx.x; r < n; r += gridDim.x) {
    float v = G[(size_t)r * 256 + f];
    if (wA) sA += v * wA[r];
    if (wB) sB += v * wB[r];
    sS += v;
  }
  if (outA) atomicAdd(&outA[f], sA);
  if (outB) atomicAdd(&outB[f], sB);
  atomicAdd(&outS[f], sS);
}

// ---------------- 8 scalar reductions over d/e vectors ----------------
__global__ __launch_bounds__(256) void k_dots(const float* __restrict__ d1,
    const float* __restrict__ e1, const float* __restrict__ d2,
    const float* __restrict__ e2, float* scal, int n) {
  int i = blockIdx.x * 256 + threadIdx.x;
  float a = 0, b = 0, c = 0, d = 0;
  if (i < n) { a = d1[i]; b = e1[i]; c = d2[i]; d = e2[i]; }
  float v[8] = { b * d, b * c, b, a * d, a * c, a, d, c };
#pragma unroll
  for (int j = 0; j < 8; ++j) {
    float x = v[j];
    for (int off = 32; off; off >>= 1) x += __shfl_down(x, off);
    v[j] = x;
  }
  if ((threadIdx.x & 63) == 0)
#pragma unroll
    for (int j = 0; j < 8; ++j) atomicAdd(&scal[j], v[j]);
}

// ---------------- t_j = w_j^T C w_j ; mv_j = w_j . m_raw ----------------
__global__ __launch_bounds__(256) void k_quad(const float* __restrict__ C,
    const float* __restrict__ W1, const float* __restrict__ m_raw,
    float* __restrict__ t, float* __restrict__ mv) {
  __shared__ float w[256];
  __shared__ float r1[256], r2[256];
  int j = blockIdx.x, tid = threadIdx.x;
  w[tid] = W1[j * 256 + tid];
  __syncthreads();
  float v = 0.f;
  for (int k = 0; k < 256; ++k) v += w[k] * C[k * 256 + tid];
  r1[tid] = v * w[tid];
  r2[tid] = w[tid] * m_raw[tid];
  __syncthreads();
  for (int off = 128; off; off >>= 1) {
    if (tid < off) { r1[tid] += r1[tid + off]; r2[tid] += r2[tid + off]; }
    __syncthreads();
  }
  if (tid == 0) { t[j] = r1[0]; mv[j] = r2[0]; }
}

// ---------------- BN coefficients + x = W3 W2 c, y = W3 b2 ----------------
__global__ __launch_bounds__(256) void k_bncoef(const float* __restrict__ t,
    const float* __restrict__ mv, const float* __restrict__ b1,
    const float* __restrict__ gamma, const float* __restrict__ beta,
    const float* __restrict__ W2, const float* __restrict__ W3,
    const float* __restrict__ b2, float* Dv, float* xv, float* yv, int n) {
  __shared__ float c[256], u[256];
  int j = threadIdx.x;
  float invn = 1.f / (float)n;
  float mean = mv[j] * invn + b1[j];
  float E2 = t[j] * invn + 2.f * b1[j] * mv[j] * invn + b1[j] * b1[j];
  float var = E2 - mean * mean;
  float D = gamma[j] * rsqrtf(var + 1e-5f);
  Dv[j] = D;
  c[j] = D * (b1[j] - mean) + beta[j];
  __syncthreads();
  float uu = 0.f;
  for (int k = 0; k < 256; ++k) uu += W2[j * 256 + k] * c[k];
  u[j] = uu;
  __syncthreads();
  float xx = 0.f, yy = 0.f;
  for (int k = 0; k < 256; ++k) {
    xx += W3[j * 256 + k] * u[k];
    yy += W3[j * 256 + k] * b2[k];
  }
  xv[j] = xx;
  yv[j] = yy;
}

// ---------------- small 256x256 matmul ----------------
__global__ __launch_bounds__(256) void k_mm_small(float* __restrict__ Cm,
    const float* __restrict__ A, const float* __restrict__ B,
    const float* __restrict__ s, int transA, int transB, int accum) {
  __shared__ float a[256];
  int i = blockIdx.x, j = threadIdx.x;
  float av = transA ? A[j * 256 + i] : A[i * 256 + j];
  a[j] = s ? av * s[j] : av;
  __syncthreads();
  float acc = 0.f;
  if (transB) {
    for (int k = 0; k < 256; ++k) acc += a[k] * B[j * 256 + k];
  } else {
    for (int k = 0; k < 256; ++k) acc += a[k] * B[k * 256 + j];
  }
  if (accum) Cm[i * 256 + j] += acc;
  else Cm[i * 256 + j] = acc;
}

// ---------------- C (+)= u1 v1^T + u2 v2^T + u3 v3^T ----------------
__global__ void k_r1x3(float* __restrict__ C, const float* __restrict__ u1,
    const float* __restrict__ v1, const float* __restrict__ u2,
    const float* __restrict__ v2, const float* __restrict__ u3,
    const float* __restrict__ v3, int accum) {
  int i = blockIdx.x, j = threadIdx.x;
  float val = u1[i] * v1[j] + u2[i] * v2[j] + u3[i] * v3[j];
  if (accum) C[i * 256 + j] += val;
  else C[i * 256 + j] = val;
}

__global__ void k_mixvec(const float* __restrict__ scal, const float* __restrict__ x2,
    const float* __restrict__ yv, const float* __restrict__ b3,
    float* s1, float* s2, float* s3, float fN) {
  int j = threadIdx.x;
  s1[j] = scal[0] * x2[j] + scal[1] * yv[j] + scal[2] * b3[j];
  s2[j] = scal[3] * x2[j] + scal[4] * yv[j] + scal[5] * b3[j];
  s3[j] = scal[6] * x2[j] + scal[7] * yv[j] + fN * b3[j];
}

extern "C" void kernel_launch(void* const* d_in, const int* in_sizes, int n_in,
                              void* d_out, int out_size, void* d_ws, size_t ws_size,
                              hipStream_t stream) {
  const float* feature = (const float*)d_in[0];
  const int* src1 = (const int*)d_in[1];
  const int* dst1 = (const int*)d_in[2];
  const int* src2 = (const int*)d_in[3];
  const int* dst2 = (const int*)d_in[4];
  const float* W1 = (const float*)d_in[5];
  const float* b1 = (const float*)d_in[6];
  const float* W2 = (const float*)d_in[7];
  const float* b2 = (const float*)d_in[8];
  const float* W3 = (const float*)d_in[9];
  const float* b3 = (const float*)d_in[10];
  const float* gamma = (const float*)d_in[11];
  const float* beta = (const float*)d_in[12];
  const int N = in_sizes[0] / FDIM;
  const int E = in_sizes[1];
  float* out = (float*)d_out;

  // ---- workspace layout ----
  float* X = (float*)d_ws;
  size_t NF = (size_t)N * FDIM;
  float* Y = X + NF;
  float* G2A = Y + NF;
  int* rowptr = (int*)(G2A + NF);
  int* cursor = rowptr + (N + 1);
  int* esrc = cursor + N;
  float* vtmp = (float*)(esrc + E);
  float* d1 = vtmp + N; float* e1 = d1 + N; float* d2 = e1 + N; float* e2 = d2 + N;
  float* C = e2 + N;
  float* m_raw = C + 65536;
  float* tq = m_raw + 256; float* mv = tq + 256;
  float* Dv = mv + 256; float* x1 = Dv + 256; float* x2 = x1 + 256; float* yv = x2 + 256;
  float* Q = yv + 256; float* R1 = Q + 65536; float* R2 = R1 + 65536;
  float* Z = R2 + 65536; float* K1 = Z + 65536; float* Lm = K1 + 65536;
  float* p1 = Lm + 65536; float* p2 = p1 + 256; float* p3 = p2 + 256;
  float* q1 = p3 + 256; float* q2 = q1 + 256; float* q3 = q2 + 256;
  float* scal = q3 + 256;
  float* s1 = scal + 16; float* s2 = s1 + 256; float* s3 = s2 + 256;
  int* blksum = (int*)(s3 + 256);
  int* blkoff = blksum + 1024;
  float* partial = X;   // GRAM_KS*65536 = 12.58M floats <= NF (12.8M); X dead at gram time

  const int eb = (E + 255) / 256;
  const int nb = (N + 255) / 256;
  const int aggb = (N + 3) / 4;        // one wave per node, 4 waves/block
  const int avb = (N + 15) / 16;       // 16 threads per node
  const int nblk = (N + 1023) / 1024;

  auto build = [&](const int* s_, const int* d_) {
    hipMemsetAsync(cursor, 0, (size_t)N * sizeof(int), stream);
    k_hist<<<eb, 256, 0, stream>>>(d_, cursor, E);
    k_blksum<<<nblk, 256, 0, stream>>>(cursor, blksum, N);
    k_blkscan<<<1, 64, 0, stream>>>(blksum, blkoff, nblk);
    k_scan_blk<<<nblk, 256, 0, stream>>>(cursor, blkoff, rowptr, cursor, N);
    k_scatter<<<eb, 256, 0, stream>>>(s_, d_, cursor, esrc, E);
  };
  auto agg = [&](const float* in, float* o) {
    k_agg<<<aggb, 256, 0, stream>>>(in, rowptr, esrc, o, N);
  };
  auto gram = [&](const float* A_, const float* B_, float* Cout) {
    k_gram<<<dim3(2, 2, GRAM_KS), 256, 0, stream>>>(A_, B_, partial, N);
    k_gram_reduce<<<256, 256, 0, stream>>>(partial, Cout);
  };

  auto do_branch = [&](const int* s_, const int* d_, float* G2dst,
                       float* dvec, float* evec, float* xvec, float* Rdst) {
    build(s_, d_);
    agg(feature, X); agg(X, Y);                 // Y = G0
    gram(Y, Y, C);                              // C = G0^T G0 (partial aliases X)
    hipMemsetAsync(m_raw, 0, 256 * sizeof(float), stream);
    k_matvec3<<<512, 256, 0, stream>>>(Y, nullptr, nullptr, nullptr, nullptr, m_raw, N);
    k_quad<<<256, 256, 0, stream>>>(C, W1, m_raw, tq, mv);
    k_bncoef<<<1, 256, 0, stream>>>(tq, mv, b1, gamma, beta, W2, W3, b2, Dv, xvec, yv, N);
    k_mm_small<<<256, 256, 0, stream>>>(Q, W1, W2, Dv, 1, 1, 0);       // Q = W1^T D W2^T
    k_mm_small<<<256, 256, 0, stream>>>(Rdst, Q, W3, nullptr, 0, 1, 0);// R = Q W3^T
    k_deg<<<nb, 256, 0, stream>>>(rowptr, vtmp, N);
    k_aggv<<<avb, 256, 0, stream>>>(vtmp, rowptr, esrc, dvec, N);      // d = A^2 1
    k_aggv<<<avb, 256, 0, stream>>>(dvec, rowptr, esrc, vtmp, N);
    k_aggv<<<avb, 256, 0, stream>>>(vtmp, rowptr, esrc, evec, N);      // e = A^4 1
    agg(Y, X); agg(X, Y);                       // Y = A^4 F
    agg(Y, X); agg(X, G2dst);                   // G2 = A^6 F
  };

  do_branch(src1, dst1, G2A, d1, e1, x1, R1);
  do_branch(src2, dst2, Y, d2, e2, x2, R2);     // branch-2 G2 lands in Y

  // ---- final assembly ----
  hipMemsetAsync(p1, 0, (6 * 256 + 16) * sizeof(float), stream);  // p1..q3 + scal
  gram(G2A, Y, Z);                                                // Z = G2_1^T G2_2
  k_matvec3<<<512, 256, 0, stream>>>(G2A, e2, d2, p1, p2, p3, N);
  k_matvec3<<<512, 256, 0, stream>>>(Y, e1, d1, q1, q2, q3, N);
  k_dots<<<nb, 256, 0, stream>>>(d1, e1, d2, e2, scal, N);

  k_mm_small<<<256, 256, 0, stream>>>(K1, Z, R2, nullptr, 0, 0, 0);   // K1 = Z R2
  k_r1x3<<<256, 256, 0, stream>>>(K1, p1, x2, p2, yv, p3, b3, 1);
  k_r1x3<<<256, 256, 0, stream>>>(Lm, x1, q1, yv, q2, b3, q3, 0);
  k_mm_small<<<256, 256, 0, stream>>>(out, R1, K1, nullptr, 1, 0, 0); // out = R1^T K1
  k_mm_small<<<256, 256, 0, stream>>>(out, Lm, R2, nullptr, 0, 0, 1); // out += L R2
  k_mixvec<<<1, 256, 0, stream>>>(scal, x2, yv, b3, s1, s2, s3, (float)N);
  k_r1x3<<<256, 256, 0, stream>>>(out, x1, s1, yv, s2, b3, s3, 1);
}

// Round 9
// 2231.909 us; speedup vs baseline: 3.2066x; 1.0843x over previous
//
#include <hip/hip_runtime.h>

#define FDIM 256
#define GRAM_KS 192

// ---------------- CSR build ----------------
__global__ void k_hist(const int* __restrict__ dst, int* __restrict__ deg, int E) {
  int e = blockIdx.x * 256 + threadIdx.x;
  if (e < E) atomicAdd(&deg[dst[e]], 1);
}

__global__ __launch_bounds__(256) void k_blksum(const int* __restrict__ deg,
    int* __restrict__ blksum, int n) {
  int b = blockIdx.x, tid = threadIdx.x;
  int base = b * 1024 + tid * 4;
  int s = 0;
#pragma unroll
  for (int k = 0; k < 4; ++k) if (base + k < n) s += deg[base + k];
  for (int off = 32; off; off >>= 1) s += __shfl_down(s, off);
  __shared__ int ws4[4];
  if ((tid & 63) == 0) ws4[tid >> 6] = s;
  __syncthreads();
  if (tid == 0) blksum[b] = ws4[0] + ws4[1] + ws4[2] + ws4[3];
}

__global__ void k_blkscan(const int* __restrict__ blksum, int* __restrict__ blkoff, int nblk) {
  int lane = threadIdx.x;
  int carry = 0;
  for (int base = 0; base < nblk; base += 64) {
    int v = (base + lane < nblk) ? blksum[base + lane] : 0;
    int x = v;
    for (int off = 1; off < 64; off <<= 1) { int y = __shfl_up(x, off); if (lane >= off) x += y; }
    if (base + lane < nblk) blkoff[base + lane] = carry + x - v;
    carry += __shfl(x, 63);
  }
}

__global__ __launch_bounds__(256) void k_scan_blk(const int* __restrict__ deg,
    const int* __restrict__ blkoff, int* __restrict__ rowptr, int* __restrict__ cursor, int n) {
  int b = blockIdx.x, tid = threadIdx.x;
  int base = b * 1024 + tid * 4;
  int v[4];
#pragma unroll
  for (int k = 0; k < 4; ++k) v[k] = (base + k < n) ? deg[base + k] : 0;
  int s = v[0] + v[1] + v[2] + v[3];
  int lane = tid & 63, w = tid >> 6;
  int x = s;
  for (int off = 1; off < 64; off <<= 1) { int y = __shfl_up(x, off); if (lane >= off) x += y; }
  __shared__ int wsum[4];
  if (lane == 63) wsum[w] = x;
  __syncthreads();
  int wadd = 0;
  for (int i = 0; i < w; ++i) wadd += wsum[i];
  int run = blkoff[b] + wadd + x - s;
#pragma unroll
  for (int k = 0; k < 4; ++k) {
    if (base + k < n) { rowptr[base + k] = run; cursor[base + k] = run; }
    run += v[k];
  }
  if (n >= base && n <= base + 4) rowptr[n] = run;
}

__global__ void k_scatter(const int* __restrict__ src, const int* __restrict__ dst,
    int* __restrict__ cursor, int* __restrict__ esrc, int E) {
  int e = blockIdx.x * 256 + threadIdx.x;
  if (e < E) {
    int p = atomicAdd(&cursor[dst[e]], 1);
    esrc[p] = src[e];
  }
}

// ---------------- feature aggregation (proven: one wave per node, one-shot) ----------------
__global__ __launch_bounds__(256) void k_agg(const float* __restrict__ h,
    const int* __restrict__ rowptr, const int* __restrict__ esrc,
    float* __restrict__ out, int n) {
  int wid = ((blockIdx.x * 256) + threadIdx.x) >> 6;
  int lane = threadIdx.x & 63;
  if (wid >= n) return;
  int beg = rowptr[wid], end = rowptr[wid + 1];
  const float4* hv = (const float4*)h;
  float4 a0 = {0,0,0,0}, a1 = {0,0,0,0}, a2 = {0,0,0,0}, a3 = {0,0,0,0};
  int e = beg;
  for (; e + 4 <= end; e += 4) {
    int s0 = esrc[e], s1 = esrc[e + 1], s2 = esrc[e + 2], s3 = esrc[e + 3];
    float4 v0 = hv[(size_t)s0 * 64 + lane];
    float4 v1 = hv[(size_t)s1 * 64 + lane];
    float4 v2 = hv[(size_t)s2 * 64 + lane];
    float4 v3 = hv[(size_t)s3 * 64 + lane];
    a0.x += v0.x; a0.y += v0.y; a0.z += v0.z; a0.w += v0.w;
    a1.x += v1.x; a1.y += v1.y; a1.z += v1.z; a1.w += v1.w;
    a2.x += v2.x; a2.y += v2.y; a2.z += v2.z; a2.w += v2.w;
    a3.x += v3.x; a3.y += v3.y; a3.z += v3.z; a3.w += v3.w;
  }
  for (; e < end; ++e) {
    float4 v = hv[(size_t)esrc[e] * 64 + lane];
    a0.x += v.x; a0.y += v.y; a0.z += v.z; a0.w += v.w;
  }
  float4 r;
  r.x = (a0.x + a1.x) + (a2.x + a3.x);
  r.y = (a0.y + a1.y) + (a2.y + a3.y);
  r.z = (a0.z + a1.z) + (a2.z + a3.z);
  r.w = (a0.w + a1.w) + (a2.w + a3.w);
  ((float4*)out)[(size_t)wid * 64 + lane] = r;
}

// ---------------- dual-graph scalar aggregation, 16 lanes/node, deg inlined ----------------
__global__ __launch_bounds__(256) void k_aggv2(const float* __restrict__ in1,
    const float* __restrict__ in2,
    const int* __restrict__ rp1, const int* __restrict__ es1,
    const int* __restrict__ rp2, const int* __restrict__ es2,
    float* __restrict__ out1, float* __restrict__ out2, int n, int useDeg) {
  int t = blockIdx.x * 256 + threadIdx.x;
  int g = t >> 4;
  int sl = t & 15;
  if (g >= 2 * n) return;
  int which = (g >= n) ? 1 : 0;
  int node = which ? g - n : g;
  const int* rp = which ? rp2 : rp1;
  const int* es = which ? es2 : es1;
  const float* in = which ? in2 : in1;
  float* out = which ? out2 : out1;
  int beg = rp[node], end = rp[node + 1];
  float s = 0.f;
  if (useDeg) {
    for (int e = beg + sl; e < end; e += 16) {
      int v = es[e];
      s += (float)(rp[v + 1] - rp[v]);
    }
  } else {
    for (int e = beg + sl; e < end; e += 16) s += in[es[e]];
  }
#pragma unroll
  for (int off = 8; off; off >>= 1) s += __shfl_down(s, off, 16);
  if (sl == 0) out[node] = s;
}

// ---------------- Gram + fused column sums ----------------
// partial[z] = X_chunk^T Y_chunk (128x128 tile, 8x8 acc, split frags, pad 132).
// If outX (by==0 blocks): outX[0..255]+=X^T wxA, [256..511]+=X^T wxB, [512..767]+=colsum X.
// If outY (bx==0 blocks): same over Y with wyA/wyB. (null weights contribute zeros.)
__global__ __launch_bounds__(256) void k_gram(const float* __restrict__ Xm,
    const float* __restrict__ Ym, float* __restrict__ partial, int N,
    const float* __restrict__ wxA, const float* __restrict__ wxB, float* __restrict__ outX,
    const float* __restrict__ wyA, const float* __restrict__ wyB, float* __restrict__ outY) {
  __shared__ float Xs[16][132];
  __shared__ float Ys[16][132];
  __shared__ float wls[4][16];
  int tid = threadIdx.x;
  int i0 = blockIdx.x * 128, j0 = blockIdx.y * 128;
  int z = blockIdx.z;
  int chunk = (N + GRAM_KS - 1) / GRAM_KS;
  int rb = z * chunk, re = min(N, rb + chunk);
  int lk = tid >> 4;
  int tj = tid & 15;
  int lc = tj * 8;
  int ti = lk;
  bool doX = (outX != nullptr) && (blockIdx.y == 0);
  bool doY = (outY != nullptr) && (blockIdx.x == 0);
  int cc = tid & 127, hh = tid >> 7;
  float xA = 0, xB = 0, xP = 0, yA = 0, yB = 0, yP = 0;
  float acc[8][8] = {};
  for (int rr = rb; rr < re; rr += 16) {
    int r = rr + lk;
    float4 a0 = {0,0,0,0}, a1 = {0,0,0,0}, b0 = {0,0,0,0}, b1 = {0,0,0,0};
    if (r < re) {
      const float* xp = Xm + (size_t)r * 256 + i0 + lc;
      const float* yp = Ym + (size_t)r * 256 + j0 + lc;
      a0 = *(const float4*)xp; a1 = *(const float4*)(xp + 4);
      b0 = *(const float4*)yp; b1 = *(const float4*)(yp + 4);
    }
    *(float4*)&Xs[lk][lc] = a0; *(float4*)&Xs[lk][lc + 4] = a1;
    *(float4*)&Ys[lk][lc] = b0; *(float4*)&Ys[lk][lc + 4] = b1;
    if (tid < 64) {
      int grp = tid >> 4, kk = tid & 15, rw = rr + kk;
      const float* wp = (grp == 0) ? wxA : (grp == 1) ? wxB : (grp == 2) ? wyA : wyB;
      wls[grp][kk] = (wp && rw < re) ? wp[rw] : 0.f;
    }
    __syncthreads();
    if (doX) {
#pragma unroll
      for (int k = 0; k < 8; ++k) {
        float v = Xs[hh * 8 + k][cc];
        xP += v; xA += v * wls[0][hh * 8 + k]; xB += v * wls[1][hh * 8 + k];
      }
    }
    if (doY) {
#pragma unroll
      for (int k = 0; k < 8; ++k) {
        float v = Ys[hh * 8 + k][cc];
        yP += v; yA += v * wls[2][hh * 8 + k]; yB += v * wls[3][hh * 8 + k];
      }
    }
#pragma unroll
    for (int k = 0; k < 16; ++k) {
      float av[8], bv[8];
      *(float4*)&av[0] = *(const float4*)&Xs[k][ti * 4];
      *(float4*)&av[4] = *(const float4*)&Xs[k][64 + ti * 4];
      *(float4*)&bv[0] = *(const float4*)&Ys[k][tj * 4];
      *(float4*)&bv[4] = *(const float4*)&Ys[k][64 + tj * 4];
#pragma unroll
      for (int i = 0; i < 8; ++i)
#pragma unroll
        for (int j = 0; j < 8; ++j) acc[i][j] += av[i] * bv[j];
    }
    __syncthreads();
  }
  float* pout = partial + (size_t)z * 65536;
#pragma unroll
  for (int i = 0; i < 8; ++i) {
    int row = i0 + ((i < 4) ? (ti * 4 + i) : (64 + ti * 4 + i - 4));
#pragma unroll
    for (int j = 0; j < 8; j += 4) {
      int col = j0 + ((j < 4) ? (tj * 4 + j) : (64 + tj * 4 + j - 4));
      *(float4*)(pout + (size_t)row * 256 + col) = *(float4*)&acc[i][j];
    }
  }
  if (doX) {
    __syncthreads();
    Xs[hh][cc] = xA;
    __syncthreads();
    if (tid < 128) atomicAdd(&outX[i0 + tid], Xs[0][tid] + Xs[1][tid]);
    __syncthreads();
    Xs[hh][cc] = xB;
    __syncthreads();
    if (tid < 128) atomicAdd(&outX[256 + i0 + tid], Xs[0][tid] + Xs[1][tid]);
    __syncthreads();
    Xs[hh][cc] = xP;
    __syncthreads();
    if (tid < 128) atomicAdd(&outX[512 + i0 + tid], Xs[0][tid] + Xs[1][tid]);
  }
  if (doY) {
    __syncthreads();
    Ys[hh][cc] = yA;
    __syncthreads();
    if (tid < 128) atomicAdd(&outY[j0 + tid], Ys[0][tid] + Ys[1][tid]);
    __syncthreads();
    Ys[hh][cc] = yB;
    __syncthreads();
    if (tid < 128) atomicAdd(&outY[256 + j0 + tid], Ys[0][tid] + Ys[1][tid]);
    __syncthreads();
    Ys[hh][cc] = yP;
    __syncthreads();
    if (tid < 128) atomicAdd(&outY[512 + j0 + tid], Ys[0][tid] + Ys[1][tid]);
  }
}

__global__ void k_gram_reduce(const float* __restrict__ partial, float* __restrict__ C) {
  int idx = blockIdx.x * 256 + threadIdx.x;
  float s = 0.f;
  for (int z = 0; z < GRAM_KS; ++z) s += partial[(size_t)z * 65536 + idx];
  C[idx] = s;
}

// ---------------- 8 scalar reductions over d/e vectors ----------------
__global__ __launch_bounds__(256) void k_dots(const float* __restrict__ d1,
    const float* __restrict__ e1, const float* __restrict__ d2,
    const float* __restrict__ e2, float* scal, int n) {
  int i = blockIdx.x * 256 + threadIdx.x;
  float a = 0, b = 0, c = 0, d = 0;
  if (i < n) { a = d1[i]; b = e1[i]; c = d2[i]; d = e2[i]; }
  float v[8] = { b * d, b * c, b, a * d, a * c, a, d, c };
#pragma unroll
  for (int j = 0; j < 8; ++j) {
    float x = v[j];
    for (int off = 32; off; off >>= 1) x += __shfl_down(x, off);
    v[j] = x;
  }
  if ((threadIdx.x & 63) == 0)
#pragma unroll
    for (int j = 0; j < 8; ++j) atomicAdd(&scal[j], v[j]);
}

// ---------------- t_j = w_j^T C w_j ; mv_j = w_j . m_raw ----------------
__global__ __launch_bounds__(256) void k_quad(const float* __restrict__ C,
    const float* __restrict__ W1, const float* __restrict__ m_raw,
    float* __restrict__ t, float* __restrict__ mv) {
  __shared__ float w[256];
  __shared__ float r1[256], r2[256];
  int j = blockIdx.x, tid = threadIdx.x;
  w[tid] = W1[j * 256 + tid];
  __syncthreads();
  float v = 0.f;
  for (int k = 0; k < 256; ++k) v += w[k] * C[k * 256 + tid];
  r1[tid] = v * w[tid];
  r2[tid] = w[tid] * m_raw[tid];
  __syncthreads();
  for (int off = 128; off; off >>= 1) {
    if (tid < off) { r1[tid] += r1[tid + off]; r2[tid] += r2[tid + off]; }
    __syncthreads();
  }
  if (tid == 0) { t[j] = r1[0]; mv[j] = r2[0]; }
}

// ---------------- BN coefficients + x = W3 W2 c, y = W3 b2 ----------------
__global__ __launch_bounds__(256) void k_bncoef(const float* __restrict__ t,
    const float* __restrict__ mv, const float* __restrict__ b1,
    const float* __restrict__ gamma, const float* __restrict__ beta,
    const float* __restrict__ W2, const float* __restrict__ W3,
    const float* __restrict__ b2, float* Dv, float* xv, float* yv, int n) {
  __shared__ float c[256], u[256];
  int j = threadIdx.x;
  float invn = 1.f / (float)n;
  float mean = mv[j] * invn + b1[j];
  float E2 = t[j] * invn + 2.f * b1[j] * mv[j] * invn + b1[j] * b1[j];
  float var = E2 - mean * mean;
  float D = gamma[j] * rsqrtf(var + 1e-5f);
  Dv[j] = D;
  c[j] = D * (b1[j] - mean) + beta[j];
  __syncthreads();
  float uu = 0.f;
  for (int k = 0; k < 256; ++k) uu += W2[j * 256 + k] * c[k];
  u[j] = uu;
  __syncthreads();
  float xx = 0.f, yy = 0.f;
  for (int k = 0; k < 256; ++k) {
    xx += W3[j * 256 + k] * u[k];
    yy += W3[j * 256 + k] * b2[k];
  }
  xv[j] = xx;
  yv[j] = yy;
}

// ---------------- small 256x256 matmul ----------------
__global__ __launch_bounds__(256) void k_mm_small(float* __restrict__ Cm,
    const float* __restrict__ A, const float* __restrict__ B,
    const float* __restrict__ s, int transA, int transB, int accum) {
  __shared__ float a[256];
  int i = blockIdx.x, j = threadIdx.x;
  float av = transA ? A[j * 256 + i] : A[i * 256 + j];
  a[j] = s ? av * s[j] : av;
  __syncthreads();
  float acc = 0.f;
  if (transB) {
    for (int k = 0; k < 256; ++k) acc += a[k] * B[j * 256 + k];
  } else {
    for (int k = 0; k < 256; ++k) acc += a[k] * B[k * 256 + j];
  }
  if (accum) Cm[i * 256 + j] += acc;
  else Cm[i * 256 + j] = acc;
}

// ---------------- C (+)= u1 v1^T + u2 v2^T + u3 v3^T ----------------
__global__ void k_r1x3(float* __restrict__ C, const float* __restrict__ u1,
    const float* __restrict__ v1, const float* __restrict__ u2,
    const float* __restrict__ v2, const float* __restrict__ u3,
    const float* __restrict__ v3, int accum) {
  int i = blockIdx.x, j = threadIdx.x;
  float val = u1[i] * v1[j] + u2[i] * v2[j] + u3[i] * v3[j];
  if (accum) C[i * 256 + j] += val;
  else C[i * 256 + j] = val;
}

// ---------------- out += x1 s1^T + yv s2^T + b3 s3^T with s-vectors from scal ----------------
__global__ void k_r1scal(float* __restrict__ C, const float* __restrict__ x1,
    const float* __restrict__ yv, const float* __restrict__ b3,
    const float* __restrict__ x2, const float* __restrict__ scal, float fN) {
  int i = blockIdx.x, j = threadIdx.x;
  float s1 = scal[0] * x2[j] + scal[1] * yv[j] + scal[2] * b3[j];
  float s2 = scal[3] * x2[j] + scal[4] * yv[j] + scal[5] * b3[j];
  float s3 = scal[6] * x2[j] + scal[7] * yv[j] + fN * b3[j];
  C[i * 256 + j] += x1[i] * s1 + yv[i] * s2 + b3[i] * s3;
}

extern "C" void kernel_launch(void* const* d_in, const int* in_sizes, int n_in,
                              void* d_out, int out_size, void* d_ws, size_t ws_size,
                              hipStream_t stream) {
  const float* feature = (const float*)d_in[0];
  const int* src1 = (const int*)d_in[1];
  const int* dst1 = (const int*)d_in[2];
  const int* src2 = (const int*)d_in[3];
  const int* dst2 = (const int*)d_in[4];
  const float* W1 = (const float*)d_in[5];
  const float* b1 = (const float*)d_in[6];
  const float* W2 = (const float*)d_in[7];
  const float* b2 = (const float*)d_in[8];
  const float* W3 = (const float*)d_in[9];
  const float* b3 = (const float*)d_in[10];
  const float* gamma = (const float*)d_in[11];
  const float* beta = (const float*)d_in[12];
  const int N = in_sizes[0] / FDIM;
  const int E = in_sizes[1];
  float* out = (float*)d_out;

  // ---- workspace layout ----
  float* X = (float*)d_ws;
  size_t NF = (size_t)N * FDIM;
  float* Y = X + NF;
  float* G2A = Y + NF;
  int* rowptr1 = (int*)(G2A + NF);
  int* rowptr2 = rowptr1 + (N + 1);
  int* cursor = rowptr2 + (N + 1);
  int* esrc1 = cursor + N;
  int* esrc2 = esrc1 + E;
  float* vtmp1 = (float*)(esrc2 + E);
  float* vtmp2 = vtmp1 + N;
  float* d1 = vtmp2 + N; float* e1 = d1 + N; float* d2 = e1 + N; float* e2 = d2 + N;
  float* C = e2 + N;
  // contiguous zeroed accumulator span:
  float* mblkA = C + 65536;          // 768: [_,_,m_rawA]
  float* mblkB = mblkA + 768;        // 768
  float* pX = mblkB + 768;           // 768: p1|p2|p3
  float* qY = pX + 768;              // 768: q1|q2|q3
  float* scal = qY + 768;            // 16
  // non-zeroed small:
  float* tq = scal + 16; float* mv = tq + 256;
  float* Dv = mv + 256; float* x1 = Dv + 256; float* x2 = x1 + 256; float* yv = x2 + 256;
  float* Q = yv + 256; float* R1 = Q + 65536; float* R2 = R1 + 65536;
  float* Z = R2 + 65536; float* K1 = Z + 65536; float* Lm = K1 + 65536;
  int* blksum = (int*)(Lm + 65536);
  int* blkoff = blksum + 1024;
  float* partial = X;   // GRAM_KS*65536 = 12.58M floats <= NF (12.8M); X dead at gram time

  const int eb = (E + 255) / 256;
  const int nb = (N + 255) / 256;
  const int aggb = (N + 3) / 4;
  const int avb2 = (2 * N * 16 + 255) / 256;
  const int nblk = (N + 1023) / 1024;

  auto build = [&](const int* s_, const int* d_, int* rp, int* es) {
    hipMemsetAsync(cursor, 0, (size_t)N * sizeof(int), stream);
    k_hist<<<eb, 256, 0, stream>>>(d_, cursor, E);
    k_blksum<<<nblk, 256, 0, stream>>>(cursor, blksum, N);
    k_blkscan<<<1, 64, 0, stream>>>(blksum, blkoff, nblk);
    k_scan_blk<<<nblk, 256, 0, stream>>>(cursor, blkoff, rp, cursor, N);
    k_scatter<<<eb, 256, 0, stream>>>(s_, d_, cursor, es, E);
  };

  // ---- build both CSRs ----
  build(src1, dst1, rowptr1, esrc1);
  build(src2, dst2, rowptr2, esrc2);
  // zero all accumulators in one shot: mblkA..scal = 768*4+16 floats
  hipMemsetAsync(mblkA, 0, (768 * 4 + 16) * sizeof(float), stream);

  // ---- d/e vectors for both graphs (deg inlined) ----
  k_aggv2<<<avb2, 256, 0, stream>>>(nullptr, nullptr, rowptr1, esrc1, rowptr2, esrc2,
                                    d1, d2, N, 1);                    // d = A^2 1
  k_aggv2<<<avb2, 256, 0, stream>>>(d1, d2, rowptr1, esrc1, rowptr2, esrc2,
                                    vtmp1, vtmp2, N, 0);              // A^3 1
  k_aggv2<<<avb2, 256, 0, stream>>>(vtmp1, vtmp2, rowptr1, esrc1, rowptr2, esrc2,
                                    e1, e2, N, 0);                    // e = A^4 1
  k_dots<<<nb, 256, 0, stream>>>(d1, e1, d2, e2, scal, N);

  auto do_branch = [&](const int* rp, const int* es, float* G2dst,
                       float* mblk, float* xvec, float* Rdst) {
    k_agg<<<aggb, 256, 0, stream>>>(feature, rp, es, X, N);
    k_agg<<<aggb, 256, 0, stream>>>(X, rp, es, Y, N);                 // Y = G0
    k_gram<<<dim3(2, 2, GRAM_KS), 256, 0, stream>>>(Y, Y, partial, N,
        nullptr, nullptr, nullptr, nullptr, nullptr, mblk);           // + colsum -> mblk[512..]
    k_gram_reduce<<<256, 256, 0, stream>>>(partial, C);               // C = G0^T G0
    k_quad<<<256, 256, 0, stream>>>(C, W1, mblk + 512, tq, mv);
    k_bncoef<<<1, 256, 0, stream>>>(tq, mv, b1, gamma, beta, W2, W3, b2, Dv, xvec, yv, N);
    k_mm_small<<<256, 256, 0, stream>>>(Q, W1, W2, Dv, 1, 1, 0);      // Q = W1^T D W2^T
    k_mm_small<<<256, 256, 0, stream>>>(Rdst, Q, W3, nullptr, 0, 1, 0); // R = Q W3^T
    k_agg<<<aggb, 256, 0, stream>>>(Y, rp, es, X, N);
    k_agg<<<aggb, 256, 0, stream>>>(X, rp, es, Y, N);                 // A^4 F
    k_agg<<<aggb, 256, 0, stream>>>(Y, rp, es, X, N);
    k_agg<<<aggb, 256, 0, stream>>>(X, rp, es, G2dst, N);             // G2 = A^6 F
  };

  do_branch(rowptr1, esrc1, G2A, mblkA, x1, R1);
  do_branch(rowptr2, esrc2, Y, mblkB, x2, R2);    // branch-2 G2 lands in Y

  // ---- final gram with fused weighted colsums ----
  k_gram<<<dim3(2, 2, GRAM_KS), 256, 0, stream>>>(G2A, Y, partial, N,
      e2, d2, pX, e1, d1, qY);                                        // Z + p's + q's
  k_gram_reduce<<<256, 256, 0, stream>>>(partial, Z);

  k_mm_small<<<256, 256, 0, stream>>>(K1, Z, R2, nullptr, 0, 0, 0);   // K1 = Z R2
  k_r1x3<<<256, 256, 0, stream>>>(K1, pX, x2, pX + 256, yv, pX + 512, b3, 1);
  k_r1x3<<<256, 256, 0, stream>>>(Lm, x1, qY, yv, qY + 256, b3, qY + 512, 0);
  k_mm_small<<<256, 256, 0, stream>>>(out, R1, K1, nullptr, 1, 0, 0); // out = R1^T K1
  k_mm_small<<<256, 256, 0, stream>>>(out, Lm, R2, nullptr, 0, 0, 1); // out += L R2
  k_r1scal<<<256, 256, 0, stream>>>(out, x1, yv, b3, x2, scal, (float)N);
}